// Round 4
// baseline (6203.094 us; speedup 1.0000x reference)
//
#include <hip/hip_runtime.h>

#define T_TOK 4096
#define HID   2048
#define NH    32
#define HD    128
#define PP    4096

typedef unsigned short u16;
typedef unsigned int   u32;
typedef __attribute__((ext_vector_type(8))) short short8;
typedef __attribute__((ext_vector_type(4))) float floatx4;
typedef __attribute__((ext_vector_type(2))) unsigned int uint2v;

__device__ __forceinline__ float b2f(u16 u) {
  union { u32 i; float f; } x; x.i = ((u32)u) << 16; return x.f;
}
__device__ __forceinline__ u16 f2b(float f) {
  u32 x = __float_as_uint(f);
  u32 r = (x + 0x7fffu + ((x >> 16) & 1u)) >> 16;
  return (u16)r;
}
__device__ __forceinline__ float blo(u32 u) { return __uint_as_float(u << 16); }
__device__ __forceinline__ float bhi(u32 u) { return __uint_as_float(u & 0xffff0000u); }

// fast transcendentals: v_exp_f32 / v_rcp_f32 (~1ulp fp32 — far below bf16 noise)
__device__ __forceinline__ float fexp(float x) {
  return __builtin_amdgcn_exp2f(x * 1.4426950408889634f);
}
__device__ __forceinline__ float fsig(float x) {
  return __builtin_amdgcn_rcpf(1.f + fexp(-x));
}

// 64-lane sum, broadcast to all lanes. 4x DPP row_ror within 16-lane rows,
// permlane16_swap pair-add across rows (pure VALU; removes the ds_swizzle
// LDS-latency from the recurrence critical path), permlane32_swap across halves.
// Arithmetic order identical to the previous ds_swizzle version.
__device__ __forceinline__ float wsum64(float x) {
  int t;
  t = __builtin_amdgcn_update_dpp(0, __float_as_int(x), 0x121, 0xf, 0xf, true);
  x += __int_as_float(t);
  t = __builtin_amdgcn_update_dpp(0, __float_as_int(x), 0x122, 0xf, 0xf, true);
  x += __int_as_float(t);
  t = __builtin_amdgcn_update_dpp(0, __float_as_int(x), 0x124, 0xf, 0xf, true);
  x += __int_as_float(t);
  t = __builtin_amdgcn_update_dpp(0, __float_as_int(x), 0x128, 0xf, 0xf, true);
  x += __int_as_float(t);
  // each lane now holds its 16-lane row sum
#if __has_builtin(__builtin_amdgcn_permlane16_swap)
  uint2v s = __builtin_amdgcn_permlane16_swap(__float_as_uint(x), __float_as_uint(x), false, false);
  x = __uint_as_float(s[0]) + __uint_as_float(s[1]);   // x[lane] + x[lane^16]
#else
  t = __builtin_amdgcn_ds_swizzle(__float_as_int(x), 0x401F); // lane ^ 16
  x += __int_as_float(t);
#endif
  uint2v p = __builtin_amdgcn_permlane32_swap(__float_as_uint(x), __float_as_uint(x), false, false);
  return __uint_as_float(p[0]) + __uint_as_float(p[1]);
}

// ---------------- GEMM: C[M,N]bf16 = A[M,K] * B[K,N]f32 via bf16 MFMA ----------------
template<int ABF16, int ASPL, int BSPL>
__global__ __launch_bounds__(256)
void gemm_k(const void* __restrict__ Av, const float* __restrict__ B,
            u16* __restrict__ C, int M, int N, int K) {
  __shared__ u16 As[ASPL + 1][64][40];
  __shared__ u16 Bs[BSPL + 1][32][72];
  const int tid  = threadIdx.x;
  const int lane = tid & 63;
  const int wave = tid >> 6;
  const long bm = (long)blockIdx.y * 64;
  const long bn = (long)blockIdx.x * 64;
  const int wm = (wave >> 1) * 32;
  const int wn = (wave & 1) * 32;
  const int ar = tid >> 2, ac = (tid & 3) * 8;
  const int br = tid >> 3, bc = (tid & 7) * 8;
  const int q = lane >> 4, r = lane & 15;
  floatx4 acc[2][2];
#pragma unroll
  for (int i = 0; i < 2; ++i)
#pragma unroll
    for (int j = 0; j < 2; ++j) acc[i][j] = (floatx4)0.f;

  for (int k0 = 0; k0 < K; k0 += 32) {
    u16 ahi[8], alo[8], bhi8[8], blo8[8];
    if (ABF16) {
      const u16* A = (const u16*)Av;
      *(float4*)ahi = *(const float4*)(A + (bm + ar) * (long)K + k0 + ac);
    } else {
      const float* A = (const float*)Av;
      const float* ap = A + (bm + ar) * (long)K + k0 + ac;
#pragma unroll
      for (int e = 0; e < 8; ++e) {
        float x = ap[e];
        u16 hh = f2b(x);
        ahi[e] = hh;
        if (ASPL) alo[e] = f2b(x - b2f(hh));
      }
    }
    {
      const float* bp = B + (long)(k0 + br) * N + bn + bc;
#pragma unroll
      for (int e = 0; e < 8; ++e) {
        float x = bp[e];
        u16 hh = f2b(x);
        bhi8[e] = hh;
        if (BSPL) blo8[e] = f2b(x - b2f(hh));
      }
    }
    __syncthreads();
    *(float4*)&As[0][ar][ac] = *(float4*)ahi;
    *(float4*)&Bs[0][br][bc] = *(float4*)bhi8;
    if (ASPL) *(float4*)&As[ASPL][ar][ac] = *(float4*)alo;
    if (BSPL) *(float4*)&Bs[BSPL][br][bc] = *(float4*)blo8;
    __syncthreads();
    short8 afh[2], afl[2], bfh[2], bfl[2];
#pragma unroll
    for (int i = 0; i < 2; ++i) {
      afh[i] = *(const short8*)&As[0][wm + i * 16 + r][q * 8];
      if (ASPL) afl[i] = *(const short8*)&As[ASPL][wm + i * 16 + r][q * 8];
    }
#pragma unroll
    for (int i = 0; i < 2; ++i) {
      short8 th, tl;
#pragma unroll
      for (int j = 0; j < 8; ++j) {
        th[j] = (short)Bs[0][q * 8 + j][wn + i * 16 + r];
        if (BSPL) tl[j] = (short)Bs[BSPL][q * 8 + j][wn + i * 16 + r];
      }
      bfh[i] = th;
      if (BSPL) bfl[i] = tl;
    }
#pragma unroll
    for (int i = 0; i < 2; ++i)
#pragma unroll
      for (int j = 0; j < 2; ++j) {
        acc[i][j] = __builtin_amdgcn_mfma_f32_16x16x32_bf16(afh[i], bfh[j], acc[i][j], 0, 0, 0);
        if (BSPL) acc[i][j] = __builtin_amdgcn_mfma_f32_16x16x32_bf16(afh[i], bfl[j], acc[i][j], 0, 0, 0);
        if (ASPL) acc[i][j] = __builtin_amdgcn_mfma_f32_16x16x32_bf16(afl[i], bfh[j], acc[i][j], 0, 0, 0);
      }
  }
#pragma unroll
  for (int i = 0; i < 2; ++i)
#pragma unroll
    for (int j = 0; j < 2; ++j) {
      long col = bn + wn + j * 16 + r;
#pragma unroll
      for (int e = 0; e < 4; ++e) {
        long row = bm + wm + i * 16 + q * 4 + e;
        C[row * N + col] = f2b(acc[i][j][e]);
      }
    }
}

// ---------------- beta = 2*sigmoid(hs @ Wb)  [T,32] f32 ----------------
__global__ __launch_bounds__(256)
void beta_k(const float* __restrict__ hs, const float* __restrict__ Wb, float* __restrict__ beta) {
  int t = blockIdx.x * 8 + (threadIdx.x >> 5);
  int h = threadIdx.x & 31;
  const float* hrow = hs + (long)t * HID;
  float acc = 0.f;
  for (int k = 0; k < HID; ++k)
    acc += hrow[k] * Wb[k * NH + h];
  beta[t * NH + h] = 2.f * fsig(acc);
}

// ---- x = -5*sigmoid(exp(A_log[h]) * (g1pre + dt_bias)) in place bf16 (log-domain) ----
__global__ __launch_bounds__(256)
void expg_k(u16* __restrict__ g1, const float* __restrict__ dtb, const float* __restrict__ Alog) {
  int idx = blockIdx.x * 256 + threadIdx.x;
  int p = idx & (PP - 1);
  int h = p >> 7;
  float g = b2f(g1[idx]) + dtb[p];
  float a = fexp(Alog[h]);
  g1[idx] = f2b(-5.f * fsig(a * g));
}

// ---------------- fused conv+silu + gated delta-rule scan (V=2) ----------------
// One wave per (head, v-column PAIR): vc = {2*vp, 2*vp+1}. Lane owns k-channels
// {2*lane, 2*lane+1}. The per-head q/k conv+silu+decay work (previously computed
// redundantly by 128 waves/head) is now amortized over 2 outputs; the paired
// v-load / o-store are single u32 accesses. Round-0 dataflow preserved: all
// conv+silu in fp32 from raw bf16 projections, log-domain decay — no added
// bf16 round-trips (numerics-critical; rounds 1-2 failed from prepass rounding).
// Grid-limited at 2048 waves -> VGPRs are free; two independent reduction
// chains per wave supply the ILP that the halved occupancy no longer does.
__global__ __launch_bounds__(256)
void scan_k(const u16* __restrict__ preq, const u16* __restrict__ prek,
            u16* __restrict__ prev, const u16* __restrict__ gx,
            const float* __restrict__ beta,
            const float* __restrict__ cqw, const float* __restrict__ ckw,
            const float* __restrict__ cvw) {
  int wid  = blockIdx.x * 4 + (threadIdx.x >> 6);  // h*64 + vp
  int lane = threadIdx.x & 63;
  int h = wid >> 6, vp = wid & 63;
  int c0  = h * HD + 2 * lane;   // q/k channel pair
  int cv0 = h * HD + 2 * vp;     // adjacent v channel pair (wave-uniform)
  float qw[4][2], kw[4][2], vwA[4], vwB[4];
#pragma unroll
  for (int j = 0; j < 4; ++j) {
    qw[j][0] = cqw[c0 * 4 + j];       qw[j][1] = cqw[(c0 + 1) * 4 + j];
    kw[j][0] = ckw[c0 * 4 + j];       kw[j][1] = ckw[(c0 + 1) * 4 + j];
    vwA[j]   = cvw[cv0 * 4 + j];      vwB[j]   = cvw[(cv0 + 1) * 4 + j];
  }
  const u32* qp = (const u32*)preq + h * 64 + lane;
  const u32* kp = (const u32*)prek + h * 64 + lane;
  const u32* xp = (const u32*)gx   + h * 64 + lane;
  u32*       vpp = (u32*)prev + h * 64 + vp;   // two adjacent u16 = one u32
  const float* bp = beta + h;
  float hq0x = 0.f, hq0y = 0.f, hq1x = 0.f, hq1y = 0.f, hq2x = 0.f, hq2y = 0.f;
  float hk0x = 0.f, hk0y = 0.f, hk1x = 0.f, hk1y = 0.f, hk2x = 0.f, hk2y = 0.f;
  float hvA0 = 0.f, hvA1 = 0.f, hvA2 = 0.f;
  float hvB0 = 0.f, hvB1 = 0.f, hvB2 = 0.f;
  float SxA = 0.f, SyA = 0.f, SxB = 0.f, SyB = 0.f;
  const float qscale = 0.08838834764831845f;  // HD^-0.5
#pragma unroll 4
  for (int t = 0; t < T_TOK; ++t) {
    u32 qr = *qp; qp += PP / 2;
    u32 kr = *kp; kp += PP / 2;
    u32 xr = *xp; xp += PP / 2;
    u32 vr = *vpp;
    float bt = *bp; bp += NH;
    float qx = blo(qr), qy = bhi(qr);
    float kx = blo(kr), ky = bhi(kr);
    float vrA = blo(vr), vrB = bhi(vr);
    // causal conv (w[3]*x[t] + w[2]*x[t-1] + w[1]*x[t-2] + w[0]*x[t-3]), fp32
    float cq0 = qw[3][0] * qx + qw[2][0] * hq0x + qw[1][0] * hq1x + qw[0][0] * hq2x;
    float cq1 = qw[3][1] * qy + qw[2][1] * hq0y + qw[1][1] * hq1y + qw[0][1] * hq2y;
    float ck0 = kw[3][0] * kx + kw[2][0] * hk0x + kw[1][0] * hk1x + kw[0][0] * hk2x;
    float ck1 = kw[3][1] * ky + kw[2][1] * hk0y + kw[1][1] * hk1y + kw[0][1] * hk2y;
    float cvA = vwA[3] * vrA + vwA[2] * hvA0 + vwA[1] * hvA1 + vwA[0] * hvA2;
    float cvB = vwB[3] * vrB + vwB[2] * hvB0 + vwB[1] * hvB1 + vwB[0] * hvB2;
    hq2x = hq1x; hq1x = hq0x; hq0x = qx;
    hq2y = hq1y; hq1y = hq0y; hq0y = qy;
    hk2x = hk1x; hk1x = hk0x; hk0x = kx;
    hk2y = hk1y; hk1y = hk0y; hk0y = ky;
    hvA2 = hvA1; hvA1 = hvA0; hvA0 = vrA;
    hvB2 = hvB1; hvB1 = hvB0; hvB0 = vrB;
    float qv0 = cq0 * fsig(cq0) * qscale;
    float qv1 = cq1 * fsig(cq1) * qscale;
    float kv0 = ck0 * fsig(ck0);
    float kv1 = ck1 * fsig(ck1);
    float vvA = cvA * fsig(cvA);
    float vvB = cvB * fsig(cvB);
    // recurrence (two independent chains A/B share decay + k/q)
    float ex = fexp(blo(xr)), ey = fexp(bhi(xr));
    SxA *= ex; SyA *= ey;
    SxB *= ex; SyB *= ey;
    float prA = wsum64(fmaf(kv0, SxA, kv1 * SyA));
    float prB = wsum64(fmaf(kv0, SxB, kv1 * SyB));
    float uA = bt * (vvA - prA);
    float uB = bt * (vvB - prB);
    SxA = fmaf(kv0, uA, SxA); SyA = fmaf(kv1, uA, SyA);
    SxB = fmaf(kv0, uB, SxB); SyB = fmaf(kv1, uB, SyB);
    float oA = wsum64(fmaf(qv0, SxA, qv1 * SyA));
    float oB = wsum64(fmaf(qv0, SxB, qv1 * SyB));
    if (lane == 0) *vpp = (u32)f2b(oA) | ((u32)f2b(oB) << 16);
    vpp += PP / 2;
  }
}

// ---------------- rinv[t,h] = rsqrt(mean(o^2) + eps) ----------------
__global__ __launch_bounds__(256)
void rms_k(const u16* __restrict__ ob, float* __restrict__ rinv) {
  int wid  = blockIdx.x * 4 + (threadIdx.x >> 6);  // t*32 + h
  int lane = threadIdx.x & 63;
  u32 o2 = ((const u32*)ob)[(long)wid * 64 + lane];
  float ox = blo(o2), oy = bhi(o2);
  float ss = wsum64(ox * ox + oy * oy);
  if (lane == 0) rinv[wid] = rsqrtf(ss * (1.f / 128.f) + 1e-5f);
}

// ---------------- final GEMM with fused gated-RMSNorm A-staging ----------------
__global__ __launch_bounds__(256)
void gemm_final_k(const u16* __restrict__ ob, const u16* __restrict__ g2,
                  const float* __restrict__ rinv, const float* __restrict__ wn,
                  const float* __restrict__ Wo, float* __restrict__ C) {
  __shared__ u16 As[2][64][40];
  __shared__ u16 Bs[2][32][72];
  const int tid  = threadIdx.x;
  const int lane = tid & 63;
  const int wave = tid >> 6;
  const long bm = (long)blockIdx.y * 64;
  const long bn = (long)blockIdx.x * 64;
  const int wm = (wave >> 1) * 32;
  const int wn_ = (wave & 1) * 32;
  const int ar = tid >> 2, ac = (tid & 3) * 8;
  const int br = tid >> 3, bc = (tid & 7) * 8;
  const int q = lane >> 4, r = lane & 15;
  const int N = HID, K = PP;
  floatx4 acc[2][2];
#pragma unroll
  for (int i = 0; i < 2; ++i)
#pragma unroll
    for (int j = 0; j < 2; ++j) acc[i][j] = (floatx4)0.f;

  for (int k0 = 0; k0 < K; k0 += 32) {
    u16 ahi[8], alo[8], bhi8[8], blo8[8];
    {
      long t = bm + ar;
      int c = k0 + ac;
      float ri = rinv[t * NH + (c >> 7)];
      const u16* op = ob + t * PP + c;
      const u16* gp = g2 + t * PP + c;
#pragma unroll
      for (int e = 0; e < 8; ++e) {
        float a = b2f(op[e]) * ri * wn[(c & 127) + e] * fsig(b2f(gp[e]));
        u16 hh = f2b(a);
        ahi[e] = hh;
        alo[e] = f2b(a - b2f(hh));
      }
      const float* bpp = Wo + (long)(k0 + br) * N + bn + bc;
#pragma unroll
      for (int e = 0; e < 8; ++e) {
        float x = bpp[e];
        u16 hh = f2b(x);
        bhi8[e] = hh;
        blo8[e] = f2b(x - b2f(hh));
      }
    }
    __syncthreads();
    *(float4*)&As[0][ar][ac] = *(float4*)ahi;
    *(float4*)&As[1][ar][ac] = *(float4*)alo;
    *(float4*)&Bs[0][br][bc] = *(float4*)bhi8;
    *(float4*)&Bs[1][br][bc] = *(float4*)blo8;
    __syncthreads();
    short8 afh[2], afl[2], bfh[2], bfl[2];
#pragma unroll
    for (int i = 0; i < 2; ++i) {
      afh[i] = *(const short8*)&As[0][wm + i * 16 + r][q * 8];
      afl[i] = *(const short8*)&As[1][wm + i * 16 + r][q * 8];
    }
#pragma unroll
    for (int i = 0; i < 2; ++i) {
      short8 th, tl;
#pragma unroll
      for (int j = 0; j < 8; ++j) {
        th[j] = (short)Bs[0][q * 8 + j][wn_ + i * 16 + r];
        tl[j] = (short)Bs[1][q * 8 + j][wn_ + i * 16 + r];
      }
      bfh[i] = th; bfl[i] = tl;
    }
#pragma unroll
    for (int i = 0; i < 2; ++i)
#pragma unroll
      for (int j = 0; j < 2; ++j) {
        acc[i][j] = __builtin_amdgcn_mfma_f32_16x16x32_bf16(afh[i], bfh[j], acc[i][j], 0, 0, 0);
        acc[i][j] = __builtin_amdgcn_mfma_f32_16x16x32_bf16(afh[i], bfl[j], acc[i][j], 0, 0, 0);
        acc[i][j] = __builtin_amdgcn_mfma_f32_16x16x32_bf16(afl[i], bfh[j], acc[i][j], 0, 0, 0);
      }
  }
#pragma unroll
  for (int i = 0; i < 2; ++i)
#pragma unroll
    for (int j = 0; j < 2; ++j) {
      long col = bn + wn_ + j * 16 + r;
#pragma unroll
      for (int e = 0; e < 4; ++e) {
        long row = bm + wm + i * 16 + q * 4 + e;
        C[row * N + col] = acc[i][j][e];
      }
    }
}

extern "C" void kernel_launch(void* const* d_in, const int* in_sizes, int n_in,
                              void* d_out, int out_size, void* d_ws, size_t ws_size,
                              hipStream_t stream) {
  const float* hs   = (const float*)d_in[0];
  const float* Wq   = (const float*)d_in[1];
  const float* Wk   = (const float*)d_in[2];
  const float* Wv   = (const float*)d_in[3];
  const float* cq   = (const float*)d_in[4];
  const float* ck   = (const float*)d_in[5];
  const float* cv   = (const float*)d_in[6];
  const float* Wb   = (const float*)d_in[7];
  const float* Wfa  = (const float*)d_in[8];
  const float* Wfb  = (const float*)d_in[9];
  const float* dtb  = (const float*)d_in[10];
  const float* Alog = (const float*)d_in[11];
  const float* Wga  = (const float*)d_in[12];
  const float* Wgb  = (const float*)d_in[13];
  const float* wn   = (const float*)d_in[14];
  const float* Wo   = (const float*)d_in[15];

  char* ws = (char*)d_ws;
  const size_t SZB = (size_t)T_TOK * PP * 2;     // 32 MiB per bf16 [T,P]
  u16*   B0   = (u16*)(ws + 0 * SZB);            // pre_q raw
  u16*   B1   = (u16*)(ws + 1 * SZB);            // pre_k raw; after scan: g2pre
  u16*   B2   = (u16*)(ws + 2 * SZB);            // pre_v raw -> o (in-place)
  u16*   B3   = (u16*)(ws + 3 * SZB);            // g1pre -> log-domain decay x
  float* beta = (float*)(ws + 4 * SZB);                      // 512 KiB
  float* rinv = (float*)(ws + 4 * SZB + (512u << 10));       // 512 KiB
  u16*   hfa  = (u16*)(ws + 4 * SZB + (1u << 20));           // [T,128] bf16, 1 MiB
  u16*   hga  = (u16*)(ws + 4 * SZB + (2u << 20));           // [T,128] bf16, 1 MiB
  // total extent: 128 MiB + 3 MiB (identical to round 3, which ran)

  dim3 blk(256);
  dim3 g_big(PP / 64, T_TOK / 64);
  dim3 g_thin(HD / 64, T_TOK / 64);
  const int EW = T_TOK * PP / 256;

  // raw projections (split = fp32-quality), stored bf16
  gemm_k<0, 1, 1><<<g_big, blk, 0, stream>>>(hs, Wq, B0, T_TOK, PP, HID);
  gemm_k<0, 1, 1><<<g_big, blk, 0, stream>>>(hs, Wk, B1, T_TOK, PP, HID);
  gemm_k<0, 1, 1><<<g_big, blk, 0, stream>>>(hs, Wv, B2, T_TOK, PP, HID);
  // beta (fp32 scalar dot)
  beta_k<<<T_TOK / 8, blk, 0, stream>>>(hs, Wb, beta);
  // g1 path -> log-domain decay x in B3
  gemm_k<0, 1, 1><<<g_thin, blk, 0, stream>>>(hs, Wfa, hfa, T_TOK, HD, HID);
  gemm_k<1, 0, 1><<<g_big, blk, 0, stream>>>(hfa, Wfb, B3, T_TOK, PP, HD);
  expg_k<<<EW, blk, 0, stream>>>(B3, dtb, Alog);
  // g2 first stage
  gemm_k<0, 1, 1><<<g_thin, blk, 0, stream>>>(hs, Wga, hga, T_TOK, HD, HID);
  // fused conv+silu+scan, 2 v-columns per wave (o -> B2 in place)
  scan_k<<<NH * (HD / 2) / 4, blk, 0, stream>>>(B0, B1, B2, B3, beta, cq, ck, cv);
  // g2 second stage into freed B1
  gemm_k<1, 0, 1><<<g_big, blk, 0, stream>>>(hga, Wgb, B1, T_TOK, PP, HD);
  // rms factors
  rms_k<<<T_TOK * NH / 4, blk, 0, stream>>>(B2, rinv);
  // final projection with fused gated RMSNorm, fp32 out
  gemm_final_k<<<dim3(HID / 64, T_TOK / 64), blk, 0, stream>>>(B2, B1, rinv, wn, Wo, (float*)d_out);
}

// Round 5
// 5167.014 us; speedup vs baseline: 1.2005x; 1.2005x over previous
//
#include <hip/hip_runtime.h>

#define T_TOK 4096
#define HID   2048
#define NH    32
#define HD    128
#define PP    4096

typedef unsigned short u16;
typedef unsigned int   u32;
typedef __attribute__((ext_vector_type(8))) short short8;
typedef __attribute__((ext_vector_type(4))) float floatx4;
typedef __attribute__((ext_vector_type(2))) unsigned int uint2v;

__device__ __forceinline__ float b2f(u16 u) {
  union { u32 i; float f; } x; x.i = ((u32)u) << 16; return x.f;
}
__device__ __forceinline__ u16 f2b(float f) {
  u32 x = __float_as_uint(f);
  u32 r = (x + 0x7fffu + ((x >> 16) & 1u)) >> 16;
  return (u16)r;
}
__device__ __forceinline__ float blo(u32 u) { return __uint_as_float(u << 16); }
__device__ __forceinline__ float bhi(u32 u) { return __uint_as_float(u & 0xffff0000u); }

// fast transcendentals: v_exp_f32 / v_rcp_f32 (~1ulp fp32 — far below bf16 noise)
__device__ __forceinline__ float fexp(float x) {
  return __builtin_amdgcn_exp2f(x * 1.4426950408889634f);
}
__device__ __forceinline__ float fsig(float x) {
  return __builtin_amdgcn_rcpf(1.f + fexp(-x));
}

// 64-lane sum, broadcast to all lanes. 4x DPP row_ror within 16-lane rows,
// permlane16_swap pair-add across rows (pure VALU), permlane32_swap across
// halves. Arithmetic order identical to the ds_swizzle version.
__device__ __forceinline__ float wsum64(float x) {
  int t;
  t = __builtin_amdgcn_update_dpp(0, __float_as_int(x), 0x121, 0xf, 0xf, true);
  x += __int_as_float(t);
  t = __builtin_amdgcn_update_dpp(0, __float_as_int(x), 0x122, 0xf, 0xf, true);
  x += __int_as_float(t);
  t = __builtin_amdgcn_update_dpp(0, __float_as_int(x), 0x124, 0xf, 0xf, true);
  x += __int_as_float(t);
  t = __builtin_amdgcn_update_dpp(0, __float_as_int(x), 0x128, 0xf, 0xf, true);
  x += __int_as_float(t);
#if __has_builtin(__builtin_amdgcn_permlane16_swap)
  uint2v s = __builtin_amdgcn_permlane16_swap(__float_as_uint(x), __float_as_uint(x), false, false);
  x = __uint_as_float(s[0]) + __uint_as_float(s[1]);   // x[lane] + x[lane^16]
#else
  t = __builtin_amdgcn_ds_swizzle(__float_as_int(x), 0x401F); // lane ^ 16
  x += __int_as_float(t);
#endif
  uint2v p = __builtin_amdgcn_permlane32_swap(__float_as_uint(x), __float_as_uint(x), false, false);
  return __uint_as_float(p[0]) + __uint_as_float(p[1]);
}

// ---------------- GEMM: C[M,N]bf16 = A[M,K] * B[K,N]f32 via bf16 MFMA ----------------
template<int ABF16, int ASPL, int BSPL>
__global__ __launch_bounds__(256)
void gemm_k(const void* __restrict__ Av, const float* __restrict__ B,
            u16* __restrict__ C, int M, int N, int K) {
  __shared__ u16 As[ASPL + 1][64][40];
  __shared__ u16 Bs[BSPL + 1][32][72];
  const int tid  = threadIdx.x;
  const int lane = tid & 63;
  const int wave = tid >> 6;
  const long bm = (long)blockIdx.y * 64;
  const long bn = (long)blockIdx.x * 64;
  const int wm = (wave >> 1) * 32;
  const int wn = (wave & 1) * 32;
  const int ar = tid >> 2, ac = (tid & 3) * 8;
  const int br = tid >> 3, bc = (tid & 7) * 8;
  const int q = lane >> 4, r = lane & 15;
  floatx4 acc[2][2];
#pragma unroll
  for (int i = 0; i < 2; ++i)
#pragma unroll
    for (int j = 0; j < 2; ++j) acc[i][j] = (floatx4)0.f;

  for (int k0 = 0; k0 < K; k0 += 32) {
    u16 ahi[8], alo[8], bhi8[8], blo8[8];
    if (ABF16) {
      const u16* A = (const u16*)Av;
      *(float4*)ahi = *(const float4*)(A + (bm + ar) * (long)K + k0 + ac);
    } else {
      const float* A = (const float*)Av;
      const float* ap = A + (bm + ar) * (long)K + k0 + ac;
#pragma unroll
      for (int e = 0; e < 8; ++e) {
        float x = ap[e];
        u16 hh = f2b(x);
        ahi[e] = hh;
        if (ASPL) alo[e] = f2b(x - b2f(hh));
      }
    }
    {
      const float* bp = B + (long)(k0 + br) * N + bn + bc;
#pragma unroll
      for (int e = 0; e < 8; ++e) {
        float x = bp[e];
        u16 hh = f2b(x);
        bhi8[e] = hh;
        if (BSPL) blo8[e] = f2b(x - b2f(hh));
      }
    }
    __syncthreads();
    *(float4*)&As[0][ar][ac] = *(float4*)ahi;
    *(float4*)&Bs[0][br][bc] = *(float4*)bhi8;
    if (ASPL) *(float4*)&As[ASPL][ar][ac] = *(float4*)alo;
    if (BSPL) *(float4*)&Bs[BSPL][br][bc] = *(float4*)blo8;
    __syncthreads();
    short8 afh[2], afl[2], bfh[2], bfl[2];
#pragma unroll
    for (int i = 0; i < 2; ++i) {
      afh[i] = *(const short8*)&As[0][wm + i * 16 + r][q * 8];
      if (ASPL) afl[i] = *(const short8*)&As[ASPL][wm + i * 16 + r][q * 8];
    }
#pragma unroll
    for (int i = 0; i < 2; ++i) {
      short8 th, tl;
#pragma unroll
      for (int j = 0; j < 8; ++j) {
        th[j] = (short)Bs[0][q * 8 + j][wn + i * 16 + r];
        if (BSPL) tl[j] = (short)Bs[BSPL][q * 8 + j][wn + i * 16 + r];
      }
      bfh[i] = th;
      if (BSPL) bfl[i] = tl;
    }
#pragma unroll
    for (int i = 0; i < 2; ++i)
#pragma unroll
      for (int j = 0; j < 2; ++j) {
        acc[i][j] = __builtin_amdgcn_mfma_f32_16x16x32_bf16(afh[i], bfh[j], acc[i][j], 0, 0, 0);
        if (BSPL) acc[i][j] = __builtin_amdgcn_mfma_f32_16x16x32_bf16(afh[i], bfl[j], acc[i][j], 0, 0, 0);
        if (ASPL) acc[i][j] = __builtin_amdgcn_mfma_f32_16x16x32_bf16(afl[i], bfh[j], acc[i][j], 0, 0, 0);
      }
  }
#pragma unroll
  for (int i = 0; i < 2; ++i)
#pragma unroll
    for (int j = 0; j < 2; ++j) {
      long col = bn + wn + j * 16 + r;
#pragma unroll
      for (int e = 0; e < 4; ++e) {
        long row = bm + wm + i * 16 + q * 4 + e;
        C[row * N + col] = f2b(acc[i][j][e]);
      }
    }
}

// ---------------- beta = 2*sigmoid(hs @ Wb)  [T,32] f32 ----------------
__global__ __launch_bounds__(256)
void beta_k(const float* __restrict__ hs, const float* __restrict__ Wb, float* __restrict__ beta) {
  int t = blockIdx.x * 8 + (threadIdx.x >> 5);
  int h = threadIdx.x & 31;
  const float* hrow = hs + (long)t * HID;
  float acc = 0.f;
  for (int k = 0; k < HID; ++k)
    acc += hrow[k] * Wb[k * NH + h];
  beta[t * NH + h] = 2.f * fsig(acc);
}

// ---- x = -5*sigmoid(exp(A_log[h]) * (g1pre + dt_bias)) in place bf16 (log-domain) ----
__global__ __launch_bounds__(256)
void expg_k(u16* __restrict__ g1, const float* __restrict__ dtb, const float* __restrict__ Alog) {
  int idx = blockIdx.x * 256 + threadIdx.x;
  int p = idx & (PP - 1);
  int h = p >> 7;
  float g = b2f(g1[idx]) + dtb[p];
  float a = fexp(Alog[h]);
  g1[idx] = f2b(-5.f * fsig(a * g));
}

// ------- causal conv(K=4)+SiLU(+scale) prepass, SPLIT hi/lo bf16 output -------
// out[t,c] = u32( hi16 | lo16<<16 ) with hi+lo reconstructing the fp32 value to
// rel err <= 2^-18 — 512x tighter than the plain-bf16 prepass that failed
// accuracy in rounds 1-2. Same conv/silu arithmetic as the in-scan version.
__global__ __launch_bounds__(256)
void conv_split_k(const u16* __restrict__ x, const float* __restrict__ w,
                  u32* __restrict__ out, float scale) {
  int idx = blockIdx.x * 256 + threadIdx.x;   // T * P/8 threads
  int t = idx >> 9;                           // P/8 = 512
  int c8 = (idx & 511) << 3;
  short8 r0, r1, r2, r3;
  r3 = *(const short8*)(x + (long)t * PP + c8);
  r2 = (t >= 1) ? *(const short8*)(x + (long)(t - 1) * PP + c8) : (short8)0;
  r1 = (t >= 2) ? *(const short8*)(x + (long)(t - 2) * PP + c8) : (short8)0;
  r0 = (t >= 3) ? *(const short8*)(x + (long)(t - 3) * PP + c8) : (short8)0;
  const float4* wv = (const float4*)(w + (long)c8 * 4);
  u32 o[8];
#pragma unroll
  for (int e = 0; e < 8; ++e) {
    float4 we = wv[e];
    float s = we.x * b2f((u16)r0[e]) + we.y * b2f((u16)r1[e])
            + we.z * b2f((u16)r2[e]) + we.w * b2f((u16)r3[e]);
    float a = s * fsig(s) * scale;
    u16 hh = f2b(a);
    u16 ll = f2b(a - b2f(hh));
    o[e] = (u32)hh | ((u32)ll << 16);
  }
  *(uint4*)(out + (long)t * PP + c8)     = *(uint4*)&o[0];
  *(uint4*)(out + (long)t * PP + c8 + 4) = *(uint4*)&o[4];
}

// ---------------- gated delta-rule scan, q/k PREcomputed (split) ----------------
// V=1: one wave per (head, v-column) — 4096 waves, round-3's proven occupancy
// (round 4 showed halving waves repays instruction savings as idle slots).
// Lane owns k-channels {2*lane, 2*lane+1}: per token two 8B loads + 4 adds
// replace 16 conv FMAs + 4 quarter-rate fsig. v conv stays in-scan (in-place,
// non-redundant); decay stays log-domain bf16 + in-scan fexp (numerics-safe).
__global__ __launch_bounds__(256)
void scan_pre_k(const u32* __restrict__ qc, const u32* __restrict__ kc,
                u16* __restrict__ prev, const u16* __restrict__ gx,
                const float* __restrict__ beta, const float* __restrict__ cvw) {
  int wid  = blockIdx.x * 4 + (threadIdx.x >> 6);  // h*128 + vc
  int lane = threadIdx.x & 63;
  int h = wid >> 7, vc = wid & 127;
  int c0  = h * HD + 2 * lane;   // q/k channel pair
  int cv0 = h * HD + vc;         // v channel (wave-uniform)
  float vw0 = cvw[cv0 * 4 + 0], vw1 = cvw[cv0 * 4 + 1];
  float vw2 = cvw[cv0 * 4 + 2], vw3 = cvw[cv0 * 4 + 3];
  const u32* qp = qc + c0;
  const u32* kp = kc + c0;
  const u32* xp = (const u32*)gx + (c0 >> 1);
  u16* vp = prev + cv0;
  const float* bp = beta + h;
  float hv0 = 0.f, hv1 = 0.f, hv2 = 0.f;
  float Sx = 0.f, Sy = 0.f;
#pragma unroll 4
  for (int t = 0; t < T_TOK; ++t) {
    uint2v qu = *(const uint2v*)qp; qp += PP;
    uint2v ku = *(const uint2v*)kp; kp += PP;
    u32 xr = *xp; xp += PP / 2;
    float vraw = b2f(*vp);
    float bt = *bp; bp += NH;
    // hi+lo reconstruction (fp32-quality)
    float qv0 = blo(qu[0]) + bhi(qu[0]);
    float qv1 = blo(qu[1]) + bhi(qu[1]);
    float kv0 = blo(ku[0]) + bhi(ku[0]);
    float kv1 = blo(ku[1]) + bhi(ku[1]);
    // v causal conv + silu (wave-uniform, fp32)
    float cvv = vw3 * vraw + vw2 * hv0 + vw1 * hv1 + vw0 * hv2;
    hv2 = hv1; hv1 = hv0; hv0 = vraw;
    float vv = cvv * fsig(cvv);
    // recurrence
    Sx *= fexp(blo(xr)); Sy *= fexp(bhi(xr));
    float pr = wsum64(fmaf(kv0, Sx, kv1 * Sy));
    float u = bt * (vv - pr);
    Sx = fmaf(kv0, u, Sx);
    Sy = fmaf(kv1, u, Sy);
    float o = wsum64(fmaf(qv0, Sx, qv1 * Sy));
    if (lane == 0) *vp = f2b(o);
    vp += PP;
  }
}

// ---------------- fused conv+silu + scan (round-3 fallback, in-scan q/k) ----------------
__global__ __launch_bounds__(256)
void scan_k(const u16* __restrict__ preq, const u16* __restrict__ prek,
            u16* __restrict__ prev, const u16* __restrict__ gx,
            const float* __restrict__ beta,
            const float* __restrict__ cqw, const float* __restrict__ ckw,
            const float* __restrict__ cvw) {
  int wid  = blockIdx.x * 4 + (threadIdx.x >> 6);  // h*128 + vc
  int lane = threadIdx.x & 63;
  int h = wid >> 7, vc = wid & 127;
  int c0  = h * HD + 2 * lane;
  int cv0 = h * HD + vc;
  float qw[4][2], kw[4][2], vw[4];
#pragma unroll
  for (int j = 0; j < 4; ++j) {
    qw[j][0] = cqw[c0 * 4 + j];       qw[j][1] = cqw[(c0 + 1) * 4 + j];
    kw[j][0] = ckw[c0 * 4 + j];       kw[j][1] = ckw[(c0 + 1) * 4 + j];
    vw[j]    = cvw[cv0 * 4 + j];
  }
  const u32* q32 = (const u32*)preq;
  const u32* k32 = (const u32*)prek;
  const u32* x32 = (const u32*)gx;
  float hq0x = 0.f, hq0y = 0.f, hq1x = 0.f, hq1y = 0.f, hq2x = 0.f, hq2y = 0.f;
  float hk0x = 0.f, hk0y = 0.f, hk1x = 0.f, hk1y = 0.f, hk2x = 0.f, hk2y = 0.f;
  float hv0 = 0.f, hv1 = 0.f, hv2 = 0.f;
  float Sx = 0.f, Sy = 0.f;
  const float qscale = 0.08838834764831845f;  // HD^-0.5
#pragma unroll 4
  for (int t = 0; t < T_TOK; ++t) {
    int rb = t * (PP / 2) + h * 64 + lane;
    u32 qr = q32[rb], kr = k32[rb], xr = x32[rb];
    float vraw = b2f(prev[t * PP + cv0]);
    float bt = beta[t * NH + h];
    float qx = blo(qr), qy = bhi(qr);
    float kx = blo(kr), ky = bhi(kr);
    float cq0 = qw[3][0] * qx + qw[2][0] * hq0x + qw[1][0] * hq1x + qw[0][0] * hq2x;
    float cq1 = qw[3][1] * qy + qw[2][1] * hq0y + qw[1][1] * hq1y + qw[0][1] * hq2y;
    float ck0 = kw[3][0] * kx + kw[2][0] * hk0x + kw[1][0] * hk1x + kw[0][0] * hk2x;
    float ck1 = kw[3][1] * ky + kw[2][1] * hk0y + kw[1][1] * hk1y + kw[0][1] * hk2y;
    float cvv = vw[3] * vraw + vw[2] * hv0 + vw[1] * hv1 + vw[0] * hv2;
    hq2x = hq1x; hq1x = hq0x; hq0x = qx;
    hq2y = hq1y; hq1y = hq0y; hq0y = qy;
    hk2x = hk1x; hk1x = hk0x; hk0x = kx;
    hk2y = hk1y; hk1y = hk0y; hk0y = ky;
    hv2 = hv1; hv1 = hv0; hv0 = vraw;
    float qv0 = cq0 * fsig(cq0) * qscale;
    float qv1 = cq1 * fsig(cq1) * qscale;
    float kv0 = ck0 * fsig(ck0);
    float kv1 = ck1 * fsig(ck1);
    float vv  = cvv * fsig(cvv);
    Sx *= fexp(blo(xr)); Sy *= fexp(bhi(xr));
    float pr = wsum64(fmaf(kv0, Sx, kv1 * Sy));
    float u = bt * (vv - pr);
    Sx = fmaf(kv0, u, Sx);
    Sy = fmaf(kv1, u, Sy);
    float o = wsum64(fmaf(qv0, Sx, qv1 * Sy));
    if (lane == 0) prev[t * PP + cv0] = f2b(o);
  }
}

// ---------------- rinv[t,h] = rsqrt(mean(o^2) + eps) ----------------
__global__ __launch_bounds__(256)
void rms_k(const u16* __restrict__ ob, float* __restrict__ rinv) {
  int wid  = blockIdx.x * 4 + (threadIdx.x >> 6);  // t*32 + h
  int lane = threadIdx.x & 63;
  u32 o2 = ((const u32*)ob)[(long)wid * 64 + lane];
  float ox = blo(o2), oy = bhi(o2);
  float ss = wsum64(ox * ox + oy * oy);
  if (lane == 0) rinv[wid] = rsqrtf(ss * (1.f / 128.f) + 1e-5f);
}

// ---------------- final GEMM with fused gated-RMSNorm A-staging ----------------
__global__ __launch_bounds__(256)
void gemm_final_k(const u16* __restrict__ ob, const u16* __restrict__ g2,
                  const float* __restrict__ rinv, const float* __restrict__ wn,
                  const float* __restrict__ Wo, float* __restrict__ C) {
  __shared__ u16 As[2][64][40];
  __shared__ u16 Bs[2][32][72];
  const int tid  = threadIdx.x;
  const int lane = tid & 63;
  const int wave = tid >> 6;
  const long bm = (long)blockIdx.y * 64;
  const long bn = (long)blockIdx.x * 64;
  const int wm = (wave >> 1) * 32;
  const int wn_ = (wave & 1) * 32;
  const int ar = tid >> 2, ac = (tid & 3) * 8;
  const int br = tid >> 3, bc = (tid & 7) * 8;
  const int q = lane >> 4, r = lane & 15;
  const int N = HID, K = PP;
  floatx4 acc[2][2];
#pragma unroll
  for (int i = 0; i < 2; ++i)
#pragma unroll
    for (int j = 0; j < 2; ++j) acc[i][j] = (floatx4)0.f;

  for (int k0 = 0; k0 < K; k0 += 32) {
    u16 ahi[8], alo[8], bhi8[8], blo8[8];
    {
      long t = bm + ar;
      int c = k0 + ac;
      float ri = rinv[t * NH + (c >> 7)];
      const u16* op = ob + t * PP + c;
      const u16* gp = g2 + t * PP + c;
#pragma unroll
      for (int e = 0; e < 8; ++e) {
        float a = b2f(op[e]) * ri * wn[(c & 127) + e] * fsig(b2f(gp[e]));
        u16 hh = f2b(a);
        ahi[e] = hh;
        alo[e] = f2b(a - b2f(hh));
      }
      const float* bpp = Wo + (long)(k0 + br) * N + bn + bc;
#pragma unroll
      for (int e = 0; e < 8; ++e) {
        float x = bpp[e];
        u16 hh = f2b(x);
        bhi8[e] = hh;
        blo8[e] = f2b(x - b2f(hh));
      }
    }
    __syncthreads();
    *(float4*)&As[0][ar][ac] = *(float4*)ahi;
    *(float4*)&As[1][ar][ac] = *(float4*)alo;
    *(float4*)&Bs[0][br][bc] = *(float4*)bhi8;
    *(float4*)&Bs[1][br][bc] = *(float4*)blo8;
    __syncthreads();
    short8 afh[2], afl[2], bfh[2], bfl[2];
#pragma unroll
    for (int i = 0; i < 2; ++i) {
      afh[i] = *(const short8*)&As[0][wm + i * 16 + r][q * 8];
      afl[i] = *(const short8*)&As[1][wm + i * 16 + r][q * 8];
    }
#pragma unroll
    for (int i = 0; i < 2; ++i) {
      short8 th, tl;
#pragma unroll
      for (int j = 0; j < 8; ++j) {
        th[j] = (short)Bs[0][q * 8 + j][wn_ + i * 16 + r];
        tl[j] = (short)Bs[1][q * 8 + j][wn_ + i * 16 + r];
      }
      bfh[i] = th; bfl[i] = tl;
    }
#pragma unroll
    for (int i = 0; i < 2; ++i)
#pragma unroll
      for (int j = 0; j < 2; ++j) {
        acc[i][j] = __builtin_amdgcn_mfma_f32_16x16x32_bf16(afh[i], bfh[j], acc[i][j], 0, 0, 0);
        acc[i][j] = __builtin_amdgcn_mfma_f32_16x16x32_bf16(afh[i], bfl[j], acc[i][j], 0, 0, 0);
        acc[i][j] = __builtin_amdgcn_mfma_f32_16x16x32_bf16(afl[i], bfh[j], acc[i][j], 0, 0, 0);
      }
  }
#pragma unroll
  for (int i = 0; i < 2; ++i)
#pragma unroll
    for (int j = 0; j < 2; ++j) {
      long col = bn + wn_ + j * 16 + r;
#pragma unroll
      for (int e = 0; e < 4; ++e) {
        long row = bm + wm + i * 16 + q * 4 + e;
        C[row * N + col] = acc[i][j][e];
      }
    }
}

extern "C" void kernel_launch(void* const* d_in, const int* in_sizes, int n_in,
                              void* d_out, int out_size, void* d_ws, size_t ws_size,
                              hipStream_t stream) {
  const float* hs   = (const float*)d_in[0];
  const float* Wq   = (const float*)d_in[1];
  const float* Wk   = (const float*)d_in[2];
  const float* Wv   = (const float*)d_in[3];
  const float* cq   = (const float*)d_in[4];
  const float* ck   = (const float*)d_in[5];
  const float* cv   = (const float*)d_in[6];
  const float* Wb   = (const float*)d_in[7];
  const float* Wfa  = (const float*)d_in[8];
  const float* Wfb  = (const float*)d_in[9];
  const float* dtb  = (const float*)d_in[10];
  const float* Alog = (const float*)d_in[11];
  const float* Wga  = (const float*)d_in[12];
  const float* Wgb  = (const float*)d_in[13];
  const float* wn   = (const float*)d_in[14];
  const float* Wo   = (const float*)d_in[15];

  char* ws = (char*)d_ws;
  dim3 blk(256);
  dim3 g_big(PP / 64, T_TOK / 64);
  dim3 g_thin(HD / 64, T_TOK / 64);
  const int EW = T_TOK * PP / 256;
  const float qscale = 0.08838834764831845f;  // HD^-0.5

  const size_t NEED = (size_t)227 << 20;
  if (ws_size >= NEED) {
    // ---- big-workspace path: q/k conv+silu precomputed as split hi/lo ----
    u32*   qc   = (u32*)(ws);                       // 64 MiB  u32[T][P]
    u32*   kc   = (u32*)(ws + ((size_t)64 << 20));  // 64 MiB
    u16*   B2   = (u16*)(ws + ((size_t)128 << 20)); // raw v -> o in place, 32 MiB
    u16*   B3   = (u16*)(ws + ((size_t)160 << 20)); // g1pre -> log decay, 32 MiB
    u16*   G2   = (u16*)(ws + ((size_t)192 << 20)); // raw k, then g2pre, 32 MiB
    float* beta = (float*)(ws + ((size_t)224 << 20));            // 512 KiB
    float* rinv = (float*)(ws + ((size_t)224 << 20) + (512u << 10)); // 512 KiB
    u16*   hfa  = (u16*)(ws + ((size_t)225 << 20)); // 1 MiB
    u16*   hga  = (u16*)(ws + ((size_t)226 << 20)); // 1 MiB
    u16*   rawq = (u16*)d_out;  // 32 MiB scratch; dead after conv_split(q);
                                // gemm_final rewrites d_out at the very end

    gemm_k<0, 1, 1><<<g_big, blk, 0, stream>>>(hs, Wq, rawq, T_TOK, PP, HID);
    gemm_k<0, 1, 1><<<g_big, blk, 0, stream>>>(hs, Wk, G2, T_TOK, PP, HID);
    gemm_k<0, 1, 1><<<g_big, blk, 0, stream>>>(hs, Wv, B2, T_TOK, PP, HID);
    beta_k<<<T_TOK / 8, blk, 0, stream>>>(hs, Wb, beta);
    gemm_k<0, 1, 1><<<g_thin, blk, 0, stream>>>(hs, Wfa, hfa, T_TOK, HD, HID);
    gemm_k<1, 0, 1><<<g_big, blk, 0, stream>>>(hfa, Wfb, B3, T_TOK, PP, HD);
    expg_k<<<EW, blk, 0, stream>>>(B3, dtb, Alog);
    gemm_k<0, 1, 1><<<g_thin, blk, 0, stream>>>(hs, Wga, hga, T_TOK, HD, HID);
    // split-precision conv+silu prepass (q gets qscale folded in)
    conv_split_k<<<T_TOK * PP / 8 / 256, blk, 0, stream>>>(rawq, cq, qc, qscale);
    conv_split_k<<<T_TOK * PP / 8 / 256, blk, 0, stream>>>(G2, ck, kc, 1.f);
    // scan with precomputed q/k (o -> B2 in place)
    scan_pre_k<<<T_TOK / 4, blk, 0, stream>>>(qc, kc, B2, B3, beta, cv);
    gemm_k<1, 0, 1><<<g_big, blk, 0, stream>>>(hga, Wgb, G2, T_TOK, PP, HD);
    rms_k<<<T_TOK * NH / 4, blk, 0, stream>>>(B2, rinv);
    gemm_final_k<<<dim3(HID / 64, T_TOK / 64), blk, 0, stream>>>(B2, G2, rinv, wn, Wo, (float*)d_out);
  } else {
    // ---- fallback: round-3 layout/path (131 MiB, measured-good) ----
    const size_t SZB = (size_t)T_TOK * PP * 2;
    u16*   B0   = (u16*)(ws + 0 * SZB);
    u16*   B1   = (u16*)(ws + 1 * SZB);
    u16*   B2   = (u16*)(ws + 2 * SZB);
    u16*   B3   = (u16*)(ws + 3 * SZB);
    float* beta = (float*)(ws + 4 * SZB);
    float* rinv = (float*)(ws + 4 * SZB + (512u << 10));
    u16*   hfa  = (u16*)(ws + 4 * SZB + (1u << 20));
    u16*   hga  = (u16*)(ws + 4 * SZB + (2u << 20));

    gemm_k<0, 1, 1><<<g_big, blk, 0, stream>>>(hs, Wq, B0, T_TOK, PP, HID);
    gemm_k<0, 1, 1><<<g_big, blk, 0, stream>>>(hs, Wk, B1, T_TOK, PP, HID);
    gemm_k<0, 1, 1><<<g_big, blk, 0, stream>>>(hs, Wv, B2, T_TOK, PP, HID);
    beta_k<<<T_TOK / 8, blk, 0, stream>>>(hs, Wb, beta);
    gemm_k<0, 1, 1><<<g_thin, blk, 0, stream>>>(hs, Wfa, hfa, T_TOK, HD, HID);
    gemm_k<1, 0, 1><<<g_big, blk, 0, stream>>>(hfa, Wfb, B3, T_TOK, PP, HD);
    expg_k<<<EW, blk, 0, stream>>>(B3, dtb, Alog);
    gemm_k<0, 1, 1><<<g_thin, blk, 0, stream>>>(hs, Wga, hga, T_TOK, HD, HID);
    scan_k<<<T_TOK / 4, blk, 0, stream>>>(B0, B1, B2, B3, beta, cq, ck, cv);
    gemm_k<1, 0, 1><<<g_big, blk, 0, stream>>>(hga, Wgb, B1, T_TOK, PP, HD);
    rms_k<<<T_TOK * NH / 4, blk, 0, stream>>>(B2, rinv);
    gemm_final_k<<<dim3(HID / 64, T_TOK / 64), blk, 0, stream>>>(B2, B1, rinv, wn, Wo, (float*)d_out);
  }
}

// Round 6
// 4754.512 us; speedup vs baseline: 1.3047x; 1.0868x over previous
//
#include <hip/hip_runtime.h>

#define T_TOK 4096
#define HID   2048
#define NH    32
#define HD    128
#define PP    4096

typedef unsigned short u16;
typedef unsigned int   u32;
typedef __attribute__((ext_vector_type(8))) short short8;
typedef __attribute__((ext_vector_type(4))) float floatx4;
typedef __attribute__((ext_vector_type(2))) unsigned int uint2v;

__device__ __forceinline__ float b2f(u16 u) {
  union { u32 i; float f; } x; x.i = ((u32)u) << 16; return x.f;
}
__device__ __forceinline__ u16 f2b(float f) {
  u32 x = __float_as_uint(f);
  u32 r = (x + 0x7fffu + ((x >> 16) & 1u)) >> 16;
  return (u16)r;
}
__device__ __forceinline__ float blo(u32 u) { return __uint_as_float(u << 16); }
__device__ __forceinline__ float bhi(u32 u) { return __uint_as_float(u & 0xffff0000u); }

// fast transcendentals: v_exp_f32 / v_rcp_f32 (~1ulp fp32 — far below bf16 noise)
__device__ __forceinline__ float fexp(float x) {
  return __builtin_amdgcn_exp2f(x * 1.4426950408889634f);
}
__device__ __forceinline__ float fsig(float x) {
  return __builtin_amdgcn_rcpf(1.f + fexp(-x));
}

// 64-lane sum broadcast (used by rms_k and the fallback scan).
__device__ __forceinline__ float wsum64(float x) {
  int t;
  t = __builtin_amdgcn_update_dpp(0, __float_as_int(x), 0x121, 0xf, 0xf, true);
  x += __int_as_float(t);
  t = __builtin_amdgcn_update_dpp(0, __float_as_int(x), 0x122, 0xf, 0xf, true);
  x += __int_as_float(t);
  t = __builtin_amdgcn_update_dpp(0, __float_as_int(x), 0x124, 0xf, 0xf, true);
  x += __int_as_float(t);
  t = __builtin_amdgcn_update_dpp(0, __float_as_int(x), 0x128, 0xf, 0xf, true);
  x += __int_as_float(t);
#if __has_builtin(__builtin_amdgcn_permlane16_swap)
  uint2v s = __builtin_amdgcn_permlane16_swap(__float_as_uint(x), __float_as_uint(x), false, false);
  x = __uint_as_float(s[0]) + __uint_as_float(s[1]);   // x[lane] + x[lane^16]
#else
  t = __builtin_amdgcn_ds_swizzle(__float_as_int(x), 0x401F); // lane ^ 16
  x += __int_as_float(t);
#endif
  uint2v p = __builtin_amdgcn_permlane32_swap(__float_as_uint(x), __float_as_uint(x), false, false);
  return __uint_as_float(p[0]) + __uint_as_float(p[1]);
}

// 32-lane-group sum broadcast: lanes 0-31 get their group's sum, lanes 32-63
// theirs. Same DPP/permlane family as wsum64, minus the cross-half step.
__device__ __forceinline__ float wsum32h(float x) {
  int t;
  t = __builtin_amdgcn_update_dpp(0, __float_as_int(x), 0x121, 0xf, 0xf, true);
  x += __int_as_float(t);
  t = __builtin_amdgcn_update_dpp(0, __float_as_int(x), 0x122, 0xf, 0xf, true);
  x += __int_as_float(t);
  t = __builtin_amdgcn_update_dpp(0, __float_as_int(x), 0x124, 0xf, 0xf, true);
  x += __int_as_float(t);
  t = __builtin_amdgcn_update_dpp(0, __float_as_int(x), 0x128, 0xf, 0xf, true);
  x += __int_as_float(t);
#if __has_builtin(__builtin_amdgcn_permlane16_swap)
  uint2v s = __builtin_amdgcn_permlane16_swap(__float_as_uint(x), __float_as_uint(x), false, false);
  return __uint_as_float(s[0]) + __uint_as_float(s[1]);   // x[lane] + x[lane^16]
#else
  t = __builtin_amdgcn_ds_swizzle(__float_as_int(x), 0x401F); // lane ^ 16 (per 32-group)
  return x + __int_as_float(t);
#endif
}

// ---------------- GEMM: C[M,N]bf16 = A[M,K] * B[K,N]f32 via bf16 MFMA ----------------
template<int ABF16, int ASPL, int BSPL>
__global__ __launch_bounds__(256)
void gemm_k(const void* __restrict__ Av, const float* __restrict__ B,
            u16* __restrict__ C, int M, int N, int K) {
  __shared__ u16 As[ASPL + 1][64][40];
  __shared__ u16 Bs[BSPL + 1][32][72];
  const int tid  = threadIdx.x;
  const int lane = tid & 63;
  const int wave = tid >> 6;
  const long bm = (long)blockIdx.y * 64;
  const long bn = (long)blockIdx.x * 64;
  const int wm = (wave >> 1) * 32;
  const int wn = (wave & 1) * 32;
  const int ar = tid >> 2, ac = (tid & 3) * 8;
  const int br = tid >> 3, bc = (tid & 7) * 8;
  const int q = lane >> 4, r = lane & 15;
  floatx4 acc[2][2];
#pragma unroll
  for (int i = 0; i < 2; ++i)
#pragma unroll
    for (int j = 0; j < 2; ++j) acc[i][j] = (floatx4)0.f;

  for (int k0 = 0; k0 < K; k0 += 32) {
    u16 ahi[8], alo[8], bhi8[8], blo8[8];
    if (ABF16) {
      const u16* A = (const u16*)Av;
      *(float4*)ahi = *(const float4*)(A + (bm + ar) * (long)K + k0 + ac);
    } else {
      const float* A = (const float*)Av;
      const float* ap = A + (bm + ar) * (long)K + k0 + ac;
#pragma unroll
      for (int e = 0; e < 8; ++e) {
        float x = ap[e];
        u16 hh = f2b(x);
        ahi[e] = hh;
        if (ASPL) alo[e] = f2b(x - b2f(hh));
      }
    }
    {
      const float* bp = B + (long)(k0 + br) * N + bn + bc;
#pragma unroll
      for (int e = 0; e < 8; ++e) {
        float x = bp[e];
        u16 hh = f2b(x);
        bhi8[e] = hh;
        if (BSPL) blo8[e] = f2b(x - b2f(hh));
      }
    }
    __syncthreads();
    *(float4*)&As[0][ar][ac] = *(float4*)ahi;
    *(float4*)&Bs[0][br][bc] = *(float4*)bhi8;
    if (ASPL) *(float4*)&As[ASPL][ar][ac] = *(float4*)alo;
    if (BSPL) *(float4*)&Bs[BSPL][br][bc] = *(float4*)blo8;
    __syncthreads();
    short8 afh[2], afl[2], bfh[2], bfl[2];
#pragma unroll
    for (int i = 0; i < 2; ++i) {
      afh[i] = *(const short8*)&As[0][wm + i * 16 + r][q * 8];
      if (ASPL) afl[i] = *(const short8*)&As[ASPL][wm + i * 16 + r][q * 8];
    }
#pragma unroll
    for (int i = 0; i < 2; ++i) {
      short8 th, tl;
#pragma unroll
      for (int j = 0; j < 8; ++j) {
        th[j] = (short)Bs[0][q * 8 + j][wn + i * 16 + r];
        if (BSPL) tl[j] = (short)Bs[BSPL][q * 8 + j][wn + i * 16 + r];
      }
      bfh[i] = th;
      if (BSPL) bfl[i] = tl;
    }
#pragma unroll
    for (int i = 0; i < 2; ++i)
#pragma unroll
      for (int j = 0; j < 2; ++j) {
        acc[i][j] = __builtin_amdgcn_mfma_f32_16x16x32_bf16(afh[i], bfh[j], acc[i][j], 0, 0, 0);
        if (BSPL) acc[i][j] = __builtin_amdgcn_mfma_f32_16x16x32_bf16(afh[i], bfl[j], acc[i][j], 0, 0, 0);
        if (ASPL) acc[i][j] = __builtin_amdgcn_mfma_f32_16x16x32_bf16(afl[i], bfh[j], acc[i][j], 0, 0, 0);
      }
  }
#pragma unroll
  for (int i = 0; i < 2; ++i)
#pragma unroll
    for (int j = 0; j < 2; ++j) {
      long col = bn + wn + j * 16 + r;
#pragma unroll
      for (int e = 0; e < 4; ++e) {
        long row = bm + wm + i * 16 + q * 4 + e;
        C[row * N + col] = f2b(acc[i][j][e]);
      }
    }
}

// ---------------- beta = 2*sigmoid(hs @ Wb)  [T,32] f32 ----------------
__global__ __launch_bounds__(256)
void beta_k(const float* __restrict__ hs, const float* __restrict__ Wb, float* __restrict__ beta) {
  int t = blockIdx.x * 8 + (threadIdx.x >> 5);
  int h = threadIdx.x & 31;
  const float* hrow = hs + (long)t * HID;
  float acc = 0.f;
  for (int k = 0; k < HID; ++k)
    acc += hrow[k] * Wb[k * NH + h];
  beta[t * NH + h] = 2.f * fsig(acc);
}

// ---- x = -5*sigmoid(exp(A_log[h]) * (g1pre + dt_bias)) in place bf16 (log-domain) ----
// (fallback path only)
__global__ __launch_bounds__(256)
void expg_k(u16* __restrict__ g1, const float* __restrict__ dtb, const float* __restrict__ Alog) {
  int idx = blockIdx.x * 256 + threadIdx.x;
  int p = idx & (PP - 1);
  int h = p >> 7;
  float g = b2f(g1[idx]) + dtb[p];
  float a = fexp(Alog[h]);
  g1[idx] = f2b(-5.f * fsig(a * g));
}

// ---- decay prepass, EXP-domain FP32 out ----
// x = -5*sigmoid(exp(A_log[h]) * (g1pre + dt_bias)); eg = exp(bf16round(x)) f32.
// The bf16-round of x before exp makes eg BITWISE IDENTICAL to the in-scan
// fexp(bf16 x) of rounds 3/5 — zero numeric change, removes 2 trans ops/token
// from the scan. (Exp-domain *bf16* storage failed in round 1; fp32 is exact.)
__global__ __launch_bounds__(256)
void expg_f32_k(const u16* __restrict__ g1, float* __restrict__ eg,
                const float* __restrict__ dtb, const float* __restrict__ Alog) {
  int idx = blockIdx.x * 256 + threadIdx.x;
  int p = idx & (PP - 1);
  int h = p >> 7;
  float g = b2f(g1[idx]) + dtb[p];
  float a = fexp(Alog[h]);
  float x = -5.f * fsig(a * g);
  eg[idx] = fexp(b2f(f2b(x)));
}

// ------- causal conv(K=4)+SiLU(+scale) prepass, FP32 output -------
// Same conv/silu arithmetic as the in-scan version; fp32 storage is the exact
// value the round-5 hi/lo split approximated (same 4 B/channel bandwidth).
__global__ __launch_bounds__(256)
void conv_f32_k(const u16* __restrict__ x, const float* __restrict__ w,
                float* __restrict__ out, float scale) {
  int idx = blockIdx.x * 256 + threadIdx.x;   // T * P/8 threads
  int t = idx >> 9;                           // P/8 = 512
  int c8 = (idx & 511) << 3;
  short8 r0, r1, r2, r3;
  r3 = *(const short8*)(x + (long)t * PP + c8);
  r2 = (t >= 1) ? *(const short8*)(x + (long)(t - 1) * PP + c8) : (short8)0;
  r1 = (t >= 2) ? *(const short8*)(x + (long)(t - 2) * PP + c8) : (short8)0;
  r0 = (t >= 3) ? *(const short8*)(x + (long)(t - 3) * PP + c8) : (short8)0;
  const float4* wv = (const float4*)(w + (long)c8 * 4);
  float o[8];
#pragma unroll
  for (int e = 0; e < 8; ++e) {
    float4 we = wv[e];
    float s = we.x * b2f((u16)r0[e]) + we.y * b2f((u16)r1[e])
            + we.z * b2f((u16)r2[e]) + we.w * b2f((u16)r3[e]);
    o[e] = s * fsig(s) * scale;
  }
  *(float4*)(out + (long)t * PP + c8)     = *(float4*)&o[0];
  *(float4*)(out + (long)t * PP + c8 + 4) = *(float4*)&o[4];
}

// ---------------- gated delta-rule scan, HALF-WAVE column pairing ----------------
// One wave per (head, column-pair p): lanes 0-31 produce column 2p, lanes 32-63
// column 2p+1. Each lane owns 4 k-channels (l5*4..+3) — both halves cover all
// 128 channels, so q/k/decay loads are shared and ONE 32-lane reduction
// sequence yields both columns' sums simultaneously. q/k/decay are fp32
// prepass (no reconstruction, no in-scan trans for decay). v conv+silu stays
// in-scan fp32 (in-place o overwrite, non-redundant). 2048 waves (grid-limited
// ~2/SIMD): per-output issue work drops ~2.5x vs round 5, which dominates the
// VALUBusy loss at lower occupancy (round-4 lesson quantified).
__global__ __launch_bounds__(256)
void scan_half_k(const float* __restrict__ qc, const float* __restrict__ kc,
                 u16* __restrict__ prev, const float* __restrict__ eg,
                 const float* __restrict__ beta, const float* __restrict__ cvw) {
  int wid  = blockIdx.x * 4 + (threadIdx.x >> 6);  // h*64 + p
  int lane = threadIdx.x & 63;
  int h = wid >> 6, p = wid & 63;
  int hf = lane >> 5;                 // half index
  int l5 = lane & 31;
  int c0  = h * HD + l5 * 4;          // 4 channels per lane (same for both halves)
  int cv0 = h * HD + 2 * p + hf;      // column per half (uniform within half)
  float vw0 = cvw[cv0 * 4 + 0], vw1 = cvw[cv0 * 4 + 1];
  float vw2 = cvw[cv0 * 4 + 2], vw3 = cvw[cv0 * 4 + 3];
  const float4* qp = (const float4*)(qc + c0);
  const float4* kp = (const float4*)(kc + c0);
  const float4* ep = (const float4*)(eg + c0);
  u16* vp = prev + cv0;
  const float* bp = beta + h;
  float hv0 = 0.f, hv1 = 0.f, hv2 = 0.f;
  float S0 = 0.f, S1 = 0.f, S2 = 0.f, S3 = 0.f;
#pragma unroll 4
  for (int t = 0; t < T_TOK; ++t) {
    float4 qv = *qp; qp += PP / 4;
    float4 kv = *kp; kp += PP / 4;
    float4 ev = *ep; ep += PP / 4;
    float vraw = b2f(*vp);
    float bt = *bp; bp += NH;
    // v causal conv + silu (uniform within half, fp32)
    float cvv = vw3 * vraw + vw2 * hv0 + vw1 * hv1 + vw0 * hv2;
    hv2 = hv1; hv1 = hv0; hv0 = vraw;
    float vv = cvv * fsig(cvv);
    // decay (precomputed exp-domain fp32)
    S0 *= ev.x; S1 *= ev.y; S2 *= ev.z; S3 *= ev.w;
    // k . S  (4-channel per-lane partial, 32-lane tree per half)
    float pr = wsum32h(fmaf(kv.x, S0, fmaf(kv.y, S1, fmaf(kv.z, S2, kv.w * S3))));
    float u = bt * (vv - pr);
    S0 = fmaf(kv.x, u, S0); S1 = fmaf(kv.y, u, S1);
    S2 = fmaf(kv.z, u, S2); S3 = fmaf(kv.w, u, S3);
    // o = q . S (off the S-critical-path; overlaps next token)
    float o = wsum32h(fmaf(qv.x, S0, fmaf(qv.y, S1, fmaf(qv.z, S2, qv.w * S3))));
    if (l5 == 0) *vp = f2b(o);
    vp += PP;
  }
}

// ---------------- fused conv+silu + scan (round-3 fallback, in-scan q/k) ----------------
__global__ __launch_bounds__(256)
void scan_k(const u16* __restrict__ preq, const u16* __restrict__ prek,
            u16* __restrict__ prev, const u16* __restrict__ gx,
            const float* __restrict__ beta,
            const float* __restrict__ cqw, const float* __restrict__ ckw,
            const float* __restrict__ cvw) {
  int wid  = blockIdx.x * 4 + (threadIdx.x >> 6);  // h*128 + vc
  int lane = threadIdx.x & 63;
  int h = wid >> 7, vc = wid & 127;
  int c0  = h * HD + 2 * lane;
  int cv0 = h * HD + vc;
  float qw[4][2], kw[4][2], vw[4];
#pragma unroll
  for (int j = 0; j < 4; ++j) {
    qw[j][0] = cqw[c0 * 4 + j];       qw[j][1] = cqw[(c0 + 1) * 4 + j];
    kw[j][0] = ckw[c0 * 4 + j];       kw[j][1] = ckw[(c0 + 1) * 4 + j];
    vw[j]    = cvw[cv0 * 4 + j];
  }
  const u32* q32 = (const u32*)preq;
  const u32* k32 = (const u32*)prek;
  const u32* x32 = (const u32*)gx;
  float hq0x = 0.f, hq0y = 0.f, hq1x = 0.f, hq1y = 0.f, hq2x = 0.f, hq2y = 0.f;
  float hk0x = 0.f, hk0y = 0.f, hk1x = 0.f, hk1y = 0.f, hk2x = 0.f, hk2y = 0.f;
  float hv0 = 0.f, hv1 = 0.f, hv2 = 0.f;
  float Sx = 0.f, Sy = 0.f;
  const float qscale = 0.08838834764831845f;  // HD^-0.5
#pragma unroll 4
  for (int t = 0; t < T_TOK; ++t) {
    int rb = t * (PP / 2) + h * 64 + lane;
    u32 qr = q32[rb], kr = k32[rb], xr = x32[rb];
    float vraw = b2f(prev[t * PP + cv0]);
    float bt = beta[t * NH + h];
    float qx = blo(qr), qy = bhi(qr);
    float kx = blo(kr), ky = bhi(kr);
    float cq0 = qw[3][0] * qx + qw[2][0] * hq0x + qw[1][0] * hq1x + qw[0][0] * hq2x;
    float cq1 = qw[3][1] * qy + qw[2][1] * hq0y + qw[1][1] * hq1y + qw[0][1] * hq2y;
    float ck0 = kw[3][0] * kx + kw[2][0] * hk0x + kw[1][0] * hk1x + kw[0][0] * hk2x;
    float ck1 = kw[3][1] * ky + kw[2][1] * hk0y + kw[1][1] * hk1y + kw[0][1] * hk2y;
    float cvv = vw[3] * vraw + vw[2] * hv0 + vw[1] * hv1 + vw[0] * hv2;
    hq2x = hq1x; hq1x = hq0x; hq0x = qx;
    hq2y = hq1y; hq1y = hq0y; hq0y = qy;
    hk2x = hk1x; hk1x = hk0x; hk0x = kx;
    hk2y = hk1y; hk1y = hk0y; hk0y = ky;
    hv2 = hv1; hv1 = hv0; hv0 = vraw;
    float qv0 = cq0 * fsig(cq0) * qscale;
    float qv1 = cq1 * fsig(cq1) * qscale;
    float kv0 = ck0 * fsig(ck0);
    float kv1 = ck1 * fsig(ck1);
    float vv  = cvv * fsig(cvv);
    Sx *= fexp(blo(xr)); Sy *= fexp(bhi(xr));
    float pr = wsum64(fmaf(kv0, Sx, kv1 * Sy));
    float u = bt * (vv - pr);
    Sx = fmaf(kv0, u, Sx);
    Sy = fmaf(kv1, u, Sy);
    float o = wsum64(fmaf(qv0, Sx, qv1 * Sy));
    if (lane == 0) prev[t * PP + cv0] = f2b(o);
  }
}

// ---------------- rinv[t,h] = rsqrt(mean(o^2) + eps) ----------------
__global__ __launch_bounds__(256)
void rms_k(const u16* __restrict__ ob, float* __restrict__ rinv) {
  int wid  = blockIdx.x * 4 + (threadIdx.x >> 6);  // t*32 + h
  int lane = threadIdx.x & 63;
  u32 o2 = ((const u32*)ob)[(long)wid * 64 + lane];
  float ox = blo(o2), oy = bhi(o2);
  float ss = wsum64(ox * ox + oy * oy);
  if (lane == 0) rinv[wid] = rsqrtf(ss * (1.f / 128.f) + 1e-5f);
}

// ---------------- final GEMM with fused gated-RMSNorm A-staging ----------------
__global__ __launch_bounds__(256)
void gemm_final_k(const u16* __restrict__ ob, const u16* __restrict__ g2,
                  const float* __restrict__ rinv, const float* __restrict__ wn,
                  const float* __restrict__ Wo, float* __restrict__ C) {
  __shared__ u16 As[2][64][40];
  __shared__ u16 Bs[2][32][72];
  const int tid  = threadIdx.x;
  const int lane = tid & 63;
  const int wave = tid >> 6;
  const long bm = (long)blockIdx.y * 64;
  const long bn = (long)blockIdx.x * 64;
  const int wm = (wave >> 1) * 32;
  const int wn_ = (wave & 1) * 32;
  const int ar = tid >> 2, ac = (tid & 3) * 8;
  const int br = tid >> 3, bc = (tid & 7) * 8;
  const int q = lane >> 4, r = lane & 15;
  const int N = HID, K = PP;
  floatx4 acc[2][2];
#pragma unroll
  for (int i = 0; i < 2; ++i)
#pragma unroll
    for (int j = 0; j < 2; ++j) acc[i][j] = (floatx4)0.f;

  for (int k0 = 0; k0 < K; k0 += 32) {
    u16 ahi[8], alo[8], bhi8[8], blo8[8];
    {
      long t = bm + ar;
      int c = k0 + ac;
      float ri = rinv[t * NH + (c >> 7)];
      const u16* op = ob + t * PP + c;
      const u16* gp = g2 + t * PP + c;
#pragma unroll
      for (int e = 0; e < 8; ++e) {
        float a = b2f(op[e]) * ri * wn[(c & 127) + e] * fsig(b2f(gp[e]));
        u16 hh = f2b(a);
        ahi[e] = hh;
        alo[e] = f2b(a - b2f(hh));
      }
      const float* bpp = Wo + (long)(k0 + br) * N + bn + bc;
#pragma unroll
      for (int e = 0; e < 8; ++e) {
        float x = bpp[e];
        u16 hh = f2b(x);
        bhi8[e] = hh;
        blo8[e] = f2b(x - b2f(hh));
      }
    }
    __syncthreads();
    *(float4*)&As[0][ar][ac] = *(float4*)ahi;
    *(float4*)&As[1][ar][ac] = *(float4*)alo;
    *(float4*)&Bs[0][br][bc] = *(float4*)bhi8;
    *(float4*)&Bs[1][br][bc] = *(float4*)blo8;
    __syncthreads();
    short8 afh[2], afl[2], bfh[2], bfl[2];
#pragma unroll
    for (int i = 0; i < 2; ++i) {
      afh[i] = *(const short8*)&As[0][wm + i * 16 + r][q * 8];
      afl[i] = *(const short8*)&As[1][wm + i * 16 + r][q * 8];
    }
#pragma unroll
    for (int i = 0; i < 2; ++i) {
      short8 th, tl;
#pragma unroll
      for (int j = 0; j < 8; ++j) {
        th[j] = (short)Bs[0][q * 8 + j][wn_ + i * 16 + r];
        tl[j] = (short)Bs[1][q * 8 + j][wn_ + i * 16 + r];
      }
      bfh[i] = th; bfl[i] = tl;
    }
#pragma unroll
    for (int i = 0; i < 2; ++i)
#pragma unroll
      for (int j = 0; j < 2; ++j) {
        acc[i][j] = __builtin_amdgcn_mfma_f32_16x16x32_bf16(afh[i], bfh[j], acc[i][j], 0, 0, 0);
        acc[i][j] = __builtin_amdgcn_mfma_f32_16x16x32_bf16(afh[i], bfl[j], acc[i][j], 0, 0, 0);
        acc[i][j] = __builtin_amdgcn_mfma_f32_16x16x32_bf16(afl[i], bfh[j], acc[i][j], 0, 0, 0);
      }
  }
#pragma unroll
  for (int i = 0; i < 2; ++i)
#pragma unroll
    for (int j = 0; j < 2; ++j) {
      long col = bn + wn_ + j * 16 + r;
#pragma unroll
      for (int e = 0; e < 4; ++e) {
        long row = bm + wm + i * 16 + q * 4 + e;
        C[row * N + col] = acc[i][j][e];
      }
    }
}

extern "C" void kernel_launch(void* const* d_in, const int* in_sizes, int n_in,
                              void* d_out, int out_size, void* d_ws, size_t ws_size,
                              hipStream_t stream) {
  const float* hs   = (const float*)d_in[0];
  const float* Wq   = (const float*)d_in[1];
  const float* Wk   = (const float*)d_in[2];
  const float* Wv   = (const float*)d_in[3];
  const float* cq   = (const float*)d_in[4];
  const float* ck   = (const float*)d_in[5];
  const float* cv   = (const float*)d_in[6];
  const float* Wb   = (const float*)d_in[7];
  const float* Wfa  = (const float*)d_in[8];
  const float* Wfb  = (const float*)d_in[9];
  const float* dtb  = (const float*)d_in[10];
  const float* Alog = (const float*)d_in[11];
  const float* Wga  = (const float*)d_in[12];
  const float* Wgb  = (const float*)d_in[13];
  const float* wn   = (const float*)d_in[14];
  const float* Wo   = (const float*)d_in[15];

  char* ws = (char*)d_ws;
  dim3 blk(256);
  dim3 g_big(PP / 64, T_TOK / 64);
  dim3 g_thin(HD / 64, T_TOK / 64);
  const int EW = T_TOK * PP / 256;
  const float qscale = 0.08838834764831845f;  // HD^-0.5

  const size_t NEED = (size_t)227 << 20;   // same requirement round 5 proved
  if (ws_size >= NEED) {
    // ---- big path: fp32 q/k conv + fp32 exp-domain decay + half-wave scan ----
    float* qc   = (float*)(ws);                        // 64 MiB f32[T][P]
    float* kc   = (float*)(ws + ((size_t)64 << 20));   // 64 MiB
    float* egp  = (float*)(ws + ((size_t)128 << 20));  // 64 MiB (dead after scan)
    u16*   B2   = (u16*)(ws + ((size_t)192 << 20));    // raw v -> o in place, 32 MiB
    float* beta = (float*)(ws + ((size_t)224 << 20));             // 512 KiB
    float* rinv = (float*)(ws + ((size_t)224 << 20) + (512u << 10)); // 512 KiB
    u16*   hfa  = (u16*)(ws + ((size_t)225 << 20));    // 1 MiB
    u16*   hga  = (u16*)(ws + ((size_t)226 << 20));    // 1 MiB
    u16*   g1pre = (u16*)kc;        // bf16 32 MiB staged in kc region (consumed
                                    // by expg_f32 before conv k overwrites)
    u16*   G2   = (u16*)egp;        // g2pre bf16 32 MiB overlays dead eg region
    u16*   rawqk = (u16*)d_out;     // 32 MiB scratch for raw q then raw k;
                                    // gemm_final rewrites d_out at the end

    // g1 decay pipeline first (g1pre lives in kc region until consumed)
    gemm_k<0, 1, 1><<<g_thin, blk, 0, stream>>>(hs, Wfa, hfa, T_TOK, HD, HID);
    gemm_k<1, 0, 1><<<g_big, blk, 0, stream>>>(hfa, Wfb, g1pre, T_TOK, PP, HD);
    expg_f32_k<<<EW, blk, 0, stream>>>(g1pre, egp, dtb, Alog);
    // q projection -> conv+silu fp32 (qscale folded)
    gemm_k<0, 1, 1><<<g_big, blk, 0, stream>>>(hs, Wq, rawqk, T_TOK, PP, HID);
    conv_f32_k<<<T_TOK * PP / 8 / 256, blk, 0, stream>>>(rawqk, cq, qc, qscale);
    // k projection -> conv+silu fp32 (kc region: g1pre now dead)
    gemm_k<0, 1, 1><<<g_big, blk, 0, stream>>>(hs, Wk, rawqk, T_TOK, PP, HID);
    conv_f32_k<<<T_TOK * PP / 8 / 256, blk, 0, stream>>>(rawqk, ck, kc, 1.f);
    // v projection + beta + g2 first stage
    gemm_k<0, 1, 1><<<g_big, blk, 0, stream>>>(hs, Wv, B2, T_TOK, PP, HID);
    beta_k<<<T_TOK / 8, blk, 0, stream>>>(hs, Wb, beta);
    gemm_k<0, 1, 1><<<g_thin, blk, 0, stream>>>(hs, Wga, hga, T_TOK, HD, HID);
    // half-wave scan (o -> B2 in place)
    scan_half_k<<<NH * (HD / 2) / 4, blk, 0, stream>>>(qc, kc, B2, egp, beta, cv);
    // g2 second stage into dead eg region
    gemm_k<1, 0, 1><<<g_big, blk, 0, stream>>>(hga, Wgb, G2, T_TOK, PP, HD);
    rms_k<<<T_TOK * NH / 4, blk, 0, stream>>>(B2, rinv);
    gemm_final_k<<<dim3(HID / 64, T_TOK / 64), blk, 0, stream>>>(B2, G2, rinv, wn, Wo, (float*)d_out);
  } else {
    // ---- fallback: round-3 layout/path (131 MiB, measured-good) ----
    const size_t SZB = (size_t)T_TOK * PP * 2;
    u16*   B0   = (u16*)(ws + 0 * SZB);
    u16*   B1   = (u16*)(ws + 1 * SZB);
    u16*   B2   = (u16*)(ws + 2 * SZB);
    u16*   B3   = (u16*)(ws + 3 * SZB);
    float* beta = (float*)(ws + 4 * SZB);
    float* rinv = (float*)(ws + 4 * SZB + (512u << 10));
    u16*   hfa  = (u16*)(ws + 4 * SZB + (1u << 20));
    u16*   hga  = (u16*)(ws + 4 * SZB + (2u << 20));

    gemm_k<0, 1, 1><<<g_big, blk, 0, stream>>>(hs, Wq, B0, T_TOK, PP, HID);
    gemm_k<0, 1, 1><<<g_big, blk, 0, stream>>>(hs, Wk, B1, T_TOK, PP, HID);
    gemm_k<0, 1, 1><<<g_big, blk, 0, stream>>>(hs, Wv, B2, T_TOK, PP, HID);
    beta_k<<<T_TOK / 8, blk, 0, stream>>>(hs, Wb, beta);
    gemm_k<0, 1, 1><<<g_thin, blk, 0, stream>>>(hs, Wfa, hfa, T_TOK, HD, HID);
    gemm_k<1, 0, 1><<<g_big, blk, 0, stream>>>(hfa, Wfb, B3, T_TOK, PP, HD);
    expg_k<<<EW, blk, 0, stream>>>(B3, dtb, Alog);
    gemm_k<0, 1, 1><<<g_thin, blk, 0, stream>>>(hs, Wga, hga, T_TOK, HD, HID);
    scan_k<<<T_TOK / 4, blk, 0, stream>>>(B0, B1, B2, B3, beta, cq, ck, cv);
    gemm_k<1, 0, 1><<<g_big, blk, 0, stream>>>(hga, Wgb, B1, T_TOK, PP, HD);
    rms_k<<<T_TOK * NH / 4, blk, 0, stream>>>(B2, rinv);
    gemm_final_k<<<dim3(HID / 64, T_TOK / 64), blk, 0, stream>>>(B2, B1, rinv, wn, Wo, (float*)d_out);
  }
}

// Round 7
// 3765.123 us; speedup vs baseline: 1.6475x; 1.2628x over previous
//
#include <hip/hip_runtime.h>

#define T_TOK 4096
#define HID   2048
#define NH    32
#define HD    128
#define PP    4096

typedef unsigned short u16;
typedef unsigned int   u32;
typedef __attribute__((ext_vector_type(8))) short short8;
typedef __attribute__((ext_vector_type(4))) float floatx4;
typedef __attribute__((ext_vector_type(2))) unsigned int uint2v;

__device__ __forceinline__ float b2f(u16 u) {
  union { u32 i; float f; } x; x.i = ((u32)u) << 16; return x.f;
}
__device__ __forceinline__ u16 f2b(float f) {
  u32 x = __float_as_uint(f);
  u32 r = (x + 0x7fffu + ((x >> 16) & 1u)) >> 16;
  return (u16)r;
}
__device__ __forceinline__ float blo(u32 u) { return __uint_as_float(u << 16); }
__device__ __forceinline__ float bhi(u32 u) { return __uint_as_float(u & 0xffff0000u); }

// fast transcendentals: v_exp_f32 / v_rcp_f32 (~1ulp fp32 — far below bf16 noise)
__device__ __forceinline__ float fexp(float x) {
  return __builtin_amdgcn_exp2f(x * 1.4426950408889634f);
}
__device__ __forceinline__ float fsig(float x) {
  return __builtin_amdgcn_rcpf(1.f + fexp(-x));
}

// 64-lane sum broadcast (used by rms_k and the fallback scan).
__device__ __forceinline__ float wsum64(float x) {
  int t;
  t = __builtin_amdgcn_update_dpp(0, __float_as_int(x), 0x121, 0xf, 0xf, true);
  x += __int_as_float(t);
  t = __builtin_amdgcn_update_dpp(0, __float_as_int(x), 0x122, 0xf, 0xf, true);
  x += __int_as_float(t);
  t = __builtin_amdgcn_update_dpp(0, __float_as_int(x), 0x124, 0xf, 0xf, true);
  x += __int_as_float(t);
  t = __builtin_amdgcn_update_dpp(0, __float_as_int(x), 0x128, 0xf, 0xf, true);
  x += __int_as_float(t);
#if __has_builtin(__builtin_amdgcn_permlane16_swap)
  uint2v s = __builtin_amdgcn_permlane16_swap(__float_as_uint(x), __float_as_uint(x), false, false);
  x = __uint_as_float(s[0]) + __uint_as_float(s[1]);   // x[lane] + x[lane^16]
#else
  t = __builtin_amdgcn_ds_swizzle(__float_as_int(x), 0x401F); // lane ^ 16
  x += __int_as_float(t);
#endif
  uint2v p = __builtin_amdgcn_permlane32_swap(__float_as_uint(x), __float_as_uint(x), false, false);
  return __uint_as_float(p[0]) + __uint_as_float(p[1]);
}

// 32-lane-group sum broadcast: lanes 0-31 get their group's sum, lanes 32-63
// theirs. Same DPP/permlane family as wsum64, minus the cross-half step.
__device__ __forceinline__ float wsum32h(float x) {
  int t;
  t = __builtin_amdgcn_update_dpp(0, __float_as_int(x), 0x121, 0xf, 0xf, true);
  x += __int_as_float(t);
  t = __builtin_amdgcn_update_dpp(0, __float_as_int(x), 0x122, 0xf, 0xf, true);
  x += __int_as_float(t);
  t = __builtin_amdgcn_update_dpp(0, __float_as_int(x), 0x124, 0xf, 0xf, true);
  x += __int_as_float(t);
  t = __builtin_amdgcn_update_dpp(0, __float_as_int(x), 0x128, 0xf, 0xf, true);
  x += __int_as_float(t);
#if __has_builtin(__builtin_amdgcn_permlane16_swap)
  uint2v s = __builtin_amdgcn_permlane16_swap(__float_as_uint(x), __float_as_uint(x), false, false);
  return __uint_as_float(s[0]) + __uint_as_float(s[1]);   // x[lane] + x[lane^16]
#else
  t = __builtin_amdgcn_ds_swizzle(__float_as_int(x), 0x401F); // lane ^ 16 (per 32-group)
  return x + __int_as_float(t);
#endif
}

// ---------------- GEMM: C[M,N]bf16 = A[M,K] * B[K,N]f32 via bf16 MFMA ----------------
template<int ABF16, int ASPL, int BSPL>
__global__ __launch_bounds__(256)
void gemm_k(const void* __restrict__ Av, const float* __restrict__ B,
            u16* __restrict__ C, int M, int N, int K) {
  __shared__ u16 As[ASPL + 1][64][40];
  __shared__ u16 Bs[BSPL + 1][32][72];
  const int tid  = threadIdx.x;
  const int lane = tid & 63;
  const int wave = tid >> 6;
  const long bm = (long)blockIdx.y * 64;
  const long bn = (long)blockIdx.x * 64;
  const int wm = (wave >> 1) * 32;
  const int wn = (wave & 1) * 32;
  const int ar = tid >> 2, ac = (tid & 3) * 8;
  const int br = tid >> 3, bc = (tid & 7) * 8;
  const int q = lane >> 4, r = lane & 15;
  floatx4 acc[2][2];
#pragma unroll
  for (int i = 0; i < 2; ++i)
#pragma unroll
    for (int j = 0; j < 2; ++j) acc[i][j] = (floatx4)0.f;

  for (int k0 = 0; k0 < K; k0 += 32) {
    u16 ahi[8], alo[8], bhi8[8], blo8[8];
    if (ABF16) {
      const u16* A = (const u16*)Av;
      *(float4*)ahi = *(const float4*)(A + (bm + ar) * (long)K + k0 + ac);
    } else {
      const float* A = (const float*)Av;
      const float* ap = A + (bm + ar) * (long)K + k0 + ac;
#pragma unroll
      for (int e = 0; e < 8; ++e) {
        float x = ap[e];
        u16 hh = f2b(x);
        ahi[e] = hh;
        if (ASPL) alo[e] = f2b(x - b2f(hh));
      }
    }
    {
      const float* bp = B + (long)(k0 + br) * N + bn + bc;
#pragma unroll
      for (int e = 0; e < 8; ++e) {
        float x = bp[e];
        u16 hh = f2b(x);
        bhi8[e] = hh;
        if (BSPL) blo8[e] = f2b(x - b2f(hh));
      }
    }
    __syncthreads();
    *(float4*)&As[0][ar][ac] = *(float4*)ahi;
    *(float4*)&Bs[0][br][bc] = *(float4*)bhi8;
    if (ASPL) *(float4*)&As[ASPL][ar][ac] = *(float4*)alo;
    if (BSPL) *(float4*)&Bs[BSPL][br][bc] = *(float4*)blo8;
    __syncthreads();
    short8 afh[2], afl[2], bfh[2], bfl[2];
#pragma unroll
    for (int i = 0; i < 2; ++i) {
      afh[i] = *(const short8*)&As[0][wm + i * 16 + r][q * 8];
      if (ASPL) afl[i] = *(const short8*)&As[ASPL][wm + i * 16 + r][q * 8];
    }
#pragma unroll
    for (int i = 0; i < 2; ++i) {
      short8 th, tl;
#pragma unroll
      for (int j = 0; j < 8; ++j) {
        th[j] = (short)Bs[0][q * 8 + j][wn + i * 16 + r];
        if (BSPL) tl[j] = (short)Bs[BSPL][q * 8 + j][wn + i * 16 + r];
      }
      bfh[i] = th;
      if (BSPL) bfl[i] = tl;
    }
#pragma unroll
    for (int i = 0; i < 2; ++i)
#pragma unroll
      for (int j = 0; j < 2; ++j) {
        acc[i][j] = __builtin_amdgcn_mfma_f32_16x16x32_bf16(afh[i], bfh[j], acc[i][j], 0, 0, 0);
        if (BSPL) acc[i][j] = __builtin_amdgcn_mfma_f32_16x16x32_bf16(afh[i], bfl[j], acc[i][j], 0, 0, 0);
        if (ASPL) acc[i][j] = __builtin_amdgcn_mfma_f32_16x16x32_bf16(afl[i], bfh[j], acc[i][j], 0, 0, 0);
      }
  }
#pragma unroll
  for (int i = 0; i < 2; ++i)
#pragma unroll
    for (int j = 0; j < 2; ++j) {
      long col = bn + wn + j * 16 + r;
#pragma unroll
      for (int e = 0; e < 4; ++e) {
        long row = bm + wm + i * 16 + q * 4 + e;
        C[row * N + col] = f2b(acc[i][j][e]);
      }
    }
}

// ---------------- beta = 2*sigmoid(hs @ Wb)  [T,32] f32 ----------------
__global__ __launch_bounds__(256)
void beta_k(const float* __restrict__ hs, const float* __restrict__ Wb, float* __restrict__ beta) {
  int t = blockIdx.x * 8 + (threadIdx.x >> 5);
  int h = threadIdx.x & 31;
  const float* hrow = hs + (long)t * HID;
  float acc = 0.f;
  for (int k = 0; k < HID; ++k)
    acc += hrow[k] * Wb[k * NH + h];
  beta[t * NH + h] = 2.f * fsig(acc);
}

// ---- x = -5*sigmoid(exp(A_log[h]) * (g1pre + dt_bias)) in place bf16 (log-domain) ----
// (fallback path only)
__global__ __launch_bounds__(256)
void expg_k(u16* __restrict__ g1, const float* __restrict__ dtb, const float* __restrict__ Alog) {
  int idx = blockIdx.x * 256 + threadIdx.x;
  int p = idx & (PP - 1);
  int h = p >> 7;
  float g = b2f(g1[idx]) + dtb[p];
  float a = fexp(Alog[h]);
  g1[idx] = f2b(-5.f * fsig(a * g));
}

// ---- decay prepass, EXP-domain FP32 out ----
// x = -5*sigmoid(exp(A_log[h]) * (g1pre + dt_bias)); eg = exp(bf16round(x)) f32.
// Bitwise identical to the in-scan fexp(bf16 x) of rounds 3/5/6.
__global__ __launch_bounds__(256)
void expg_f32_k(const u16* __restrict__ g1, float* __restrict__ eg,
                const float* __restrict__ dtb, const float* __restrict__ Alog) {
  int idx = blockIdx.x * 256 + threadIdx.x;
  int p = idx & (PP - 1);
  int h = p >> 7;
  float g = b2f(g1[idx]) + dtb[p];
  float a = fexp(Alog[h]);
  float x = -5.f * fsig(a * g);
  eg[idx] = fexp(b2f(f2b(x)));
}

// ------- causal conv(K=4)+SiLU(+scale) prepass, FP32 output -------
__global__ __launch_bounds__(256)
void conv_f32_k(const u16* __restrict__ x, const float* __restrict__ w,
                float* __restrict__ out, float scale) {
  int idx = blockIdx.x * 256 + threadIdx.x;   // T * P/8 threads
  int t = idx >> 9;                           // P/8 = 512
  int c8 = (idx & 511) << 3;
  short8 r0, r1, r2, r3;
  r3 = *(const short8*)(x + (long)t * PP + c8);
  r2 = (t >= 1) ? *(const short8*)(x + (long)(t - 1) * PP + c8) : (short8)0;
  r1 = (t >= 2) ? *(const short8*)(x + (long)(t - 2) * PP + c8) : (short8)0;
  r0 = (t >= 3) ? *(const short8*)(x + (long)(t - 3) * PP + c8) : (short8)0;
  const float4* wv = (const float4*)(w + (long)c8 * 4);
  float o[8];
#pragma unroll
  for (int e = 0; e < 8; ++e) {
    float4 we = wv[e];
    float s = we.x * b2f((u16)r0[e]) + we.y * b2f((u16)r1[e])
            + we.z * b2f((u16)r2[e]) + we.w * b2f((u16)r3[e]);
    o[e] = s * fsig(s) * scale;
  }
  *(float4*)(out + (long)t * PP + c8)     = *(float4*)&o[0];
  *(float4*)(out + (long)t * PP + c8 + 4) = *(float4*)&o[4];
}

// ---------------- gated delta-rule scan, half-wave pairing + XCD swizzle + prefetch ----------------
// Round-6 structure (lanes 0-31 -> column 2p, lanes 32-63 -> column 2p+1; lane
// owns 4 k-channels; one 32-lane reduction serves both columns). Two
// arithmetic-neutral additions vs round 6 (which was latency-bound: VALUBusy
// 33%, FETCH 919MB vs 224MB ideal = cross-XCD re-fetch of shared per-head
// streams + too few outstanding loads at 2 waves/SIMD):
//  (1) XCD-locality swizzle: all 16 blocks of a head share bid%8, so with the
//      round-robin block->XCD dispatch one XCD's L2 serves the head's whole
//      q/k/eg stream (15 of 16 re-reads become L2 hits). Bijective remap;
//      correctness is mapping-independent.
//  (2) 4-token-group register prefetch: issue next group's loads before
//      computing the current group (~800 cyc of compute covers load latency).
//      Tail group overreads <=4 rows into the adjacent workspace region
//      (mapped; values discarded).
__global__ __launch_bounds__(256)
void scan_half_k(const float* __restrict__ qc, const float* __restrict__ kc,
                 u16* __restrict__ prev, const float* __restrict__ eg,
                 const float* __restrict__ beta, const float* __restrict__ cvw) {
  const int bid = blockIdx.x;                       // 512 blocks
  const int h   = (bid & 7) * 4 + (bid >> 7);       // head 0..31 (16 blocks/head, same bid%8)
  const int p   = ((bid >> 3) & 15) * 4 + (threadIdx.x >> 6);  // pair 0..63
  const int lane = threadIdx.x & 63;
  const int hf = lane >> 5;                 // half index
  const int l5 = lane & 31;
  const int c0  = h * HD + l5 * 4;          // 4 channels per lane (same both halves)
  const int cv0 = h * HD + 2 * p + hf;      // column per half (uniform within half)
  float vw0 = cvw[cv0 * 4 + 0], vw1 = cvw[cv0 * 4 + 1];
  float vw2 = cvw[cv0 * 4 + 2], vw3 = cvw[cv0 * 4 + 3];
  const long RS = PP / 4;                   // float4 row stride
  const float4* qp = (const float4*)(qc + c0);
  const float4* kp = (const float4*)(kc + c0);
  const float4* ep = (const float4*)(eg + c0);
  u16* vp = prev + cv0;
  const float* bp = beta + h;
  float hv0 = 0.f, hv1 = 0.f, hv2 = 0.f;
  float S0 = 0.f, S1 = 0.f, S2 = 0.f, S3 = 0.f;

  // prologue: load group 0
  float4 cq[4], ck4[4], ce[4];
  float  cvr[4], cb[4];
#pragma unroll
  for (int i = 0; i < 4; ++i) {
    cq[i]  = qp[(long)i * RS];
    ck4[i] = kp[(long)i * RS];
    ce[i]  = ep[(long)i * RS];
    cvr[i] = b2f(vp[(long)i * PP]);
    cb[i]  = bp[i * NH];
  }

  for (int tb = 0; tb < T_TOK; tb += 4) {
    // prefetch next group (rows tb+4..tb+7; benign overread on the last group)
    float4 nq[4], nk[4], ne[4];
    float  nv[4], nb[4];
#pragma unroll
    for (int i = 0; i < 4; ++i) {
      nq[i] = qp[(long)(i + 4) * RS];
      nk[i] = kp[(long)(i + 4) * RS];
      ne[i] = ep[(long)(i + 4) * RS];
      nv[i] = b2f(vp[(long)(i + 4) * PP]);
      nb[i] = bp[(i + 4) * NH];
    }
    // compute current group (arithmetic identical to round 6)
#pragma unroll
    for (int i = 0; i < 4; ++i) {
      float vraw = cvr[i];
      float bt = cb[i];
      float4 qv = cq[i], kv = ck4[i], ev = ce[i];
      float cvv = vw3 * vraw + vw2 * hv0 + vw1 * hv1 + vw0 * hv2;
      hv2 = hv1; hv1 = hv0; hv0 = vraw;
      float vv = cvv * fsig(cvv);
      S0 *= ev.x; S1 *= ev.y; S2 *= ev.z; S3 *= ev.w;
      float pr = wsum32h(fmaf(kv.x, S0, fmaf(kv.y, S1, fmaf(kv.z, S2, kv.w * S3))));
      float u = bt * (vv - pr);
      S0 = fmaf(kv.x, u, S0); S1 = fmaf(kv.y, u, S1);
      S2 = fmaf(kv.z, u, S2); S3 = fmaf(kv.w, u, S3);
      float o = wsum32h(fmaf(qv.x, S0, fmaf(qv.y, S1, fmaf(qv.z, S2, qv.w * S3))));
      if (l5 == 0) vp[(long)i * PP] = f2b(o);
    }
    // rotate buffers, advance pointers
#pragma unroll
    for (int i = 0; i < 4; ++i) {
      cq[i] = nq[i]; ck4[i] = nk[i]; ce[i] = ne[i]; cvr[i] = nv[i]; cb[i] = nb[i];
    }
    qp += 4 * RS; kp += 4 * RS; ep += 4 * RS; vp += (long)4 * PP; bp += 4 * NH;
  }
}

// ---------------- fused conv+silu + scan (round-3 fallback, in-scan q/k) ----------------
__global__ __launch_bounds__(256)
void scan_k(const u16* __restrict__ preq, const u16* __restrict__ prek,
            u16* __restrict__ prev, const u16* __restrict__ gx,
            const float* __restrict__ beta,
            const float* __restrict__ cqw, const float* __restrict__ ckw,
            const float* __restrict__ cvw) {
  int wid  = blockIdx.x * 4 + (threadIdx.x >> 6);  // h*128 + vc
  int lane = threadIdx.x & 63;
  int h = wid >> 7, vc = wid & 127;
  int c0  = h * HD + 2 * lane;
  int cv0 = h * HD + vc;
  float qw[4][2], kw[4][2], vw[4];
#pragma unroll
  for (int j = 0; j < 4; ++j) {
    qw[j][0] = cqw[c0 * 4 + j];       qw[j][1] = cqw[(c0 + 1) * 4 + j];
    kw[j][0] = ckw[c0 * 4 + j];       kw[j][1] = ckw[(c0 + 1) * 4 + j];
    vw[j]    = cvw[cv0 * 4 + j];
  }
  const u32* q32 = (const u32*)preq;
  const u32* k32 = (const u32*)prek;
  const u32* x32 = (const u32*)gx;
  float hq0x = 0.f, hq0y = 0.f, hq1x = 0.f, hq1y = 0.f, hq2x = 0.f, hq2y = 0.f;
  float hk0x = 0.f, hk0y = 0.f, hk1x = 0.f, hk1y = 0.f, hk2x = 0.f, hk2y = 0.f;
  float hv0 = 0.f, hv1 = 0.f, hv2 = 0.f;
  float Sx = 0.f, Sy = 0.f;
  const float qscale = 0.08838834764831845f;  // HD^-0.5
#pragma unroll 4
  for (int t = 0; t < T_TOK; ++t) {
    int rb = t * (PP / 2) + h * 64 + lane;
    u32 qr = q32[rb], kr = k32[rb], xr = x32[rb];
    float vraw = b2f(prev[t * PP + cv0]);
    float bt = beta[t * NH + h];
    float qx = blo(qr), qy = bhi(qr);
    float kx = blo(kr), ky = bhi(kr);
    float cq0 = qw[3][0] * qx + qw[2][0] * hq0x + qw[1][0] * hq1x + qw[0][0] * hq2x;
    float cq1 = qw[3][1] * qy + qw[2][1] * hq0y + qw[1][1] * hq1y + qw[0][1] * hq2y;
    float ck0 = kw[3][0] * kx + kw[2][0] * hk0x + kw[1][0] * hk1x + kw[0][0] * hk2x;
    float ck1 = kw[3][1] * ky + kw[2][1] * hk0y + kw[1][1] * hk1y + kw[0][1] * hk2y;
    float cvv = vw[3] * vraw + vw[2] * hv0 + vw[1] * hv1 + vw[0] * hv2;
    hq2x = hq1x; hq1x = hq0x; hq0x = qx;
    hq2y = hq1y; hq1y = hq0y; hq0y = qy;
    hk2x = hk1x; hk1x = hk0x; hk0x = kx;
    hk2y = hk1y; hk1y = hk0y; hk0y = ky;
    hv2 = hv1; hv1 = hv0; hv0 = vraw;
    float qv0 = cq0 * fsig(cq0) * qscale;
    float qv1 = cq1 * fsig(cq1) * qscale;
    float kv0 = ck0 * fsig(ck0);
    float kv1 = ck1 * fsig(ck1);
    float vv  = cvv * fsig(cvv);
    Sx *= fexp(blo(xr)); Sy *= fexp(bhi(xr));
    float pr = wsum64(fmaf(kv0, Sx, kv1 * Sy));
    float u = bt * (vv - pr);
    Sx = fmaf(kv0, u, Sx);
    Sy = fmaf(kv1, u, Sy);
    float o = wsum64(fmaf(qv0, Sx, qv1 * Sy));
    if (lane == 0) prev[t * PP + cv0] = f2b(o);
  }
}

// ---------------- rinv[t,h] = rsqrt(mean(o^2) + eps) ----------------
__global__ __launch_bounds__(256)
void rms_k(const u16* __restrict__ ob, float* __restrict__ rinv) {
  int wid  = blockIdx.x * 4 + (threadIdx.x >> 6);  // t*32 + h
  int lane = threadIdx.x & 63;
  u32 o2 = ((const u32*)ob)[(long)wid * 64 + lane];
  float ox = blo(o2), oy = bhi(o2);
  float ss = wsum64(ox * ox + oy * oy);
  if (lane == 0) rinv[wid] = rsqrtf(ss * (1.f / 128.f) + 1e-5f);
}

// ---------------- final GEMM with fused gated-RMSNorm A-staging ----------------
__global__ __launch_bounds__(256)
void gemm_final_k(const u16* __restrict__ ob, const u16* __restrict__ g2,
                  const float* __restrict__ rinv, const float* __restrict__ wn,
                  const float* __restrict__ Wo, float* __restrict__ C) {
  __shared__ u16 As[2][64][40];
  __shared__ u16 Bs[2][32][72];
  const int tid  = threadIdx.x;
  const int lane = tid & 63;
  const int wave = tid >> 6;
  const long bm = (long)blockIdx.y * 64;
  const long bn = (long)blockIdx.x * 64;
  const int wm = (wave >> 1) * 32;
  const int wn_ = (wave & 1) * 32;
  const int ar = tid >> 2, ac = (tid & 3) * 8;
  const int br = tid >> 3, bc = (tid & 7) * 8;
  const int q = lane >> 4, r = lane & 15;
  const int N = HID, K = PP;
  floatx4 acc[2][2];
#pragma unroll
  for (int i = 0; i < 2; ++i)
#pragma unroll
    for (int j = 0; j < 2; ++j) acc[i][j] = (floatx4)0.f;

  for (int k0 = 0; k0 < K; k0 += 32) {
    u16 ahi[8], alo[8], bhi8[8], blo8[8];
    {
      long t = bm + ar;
      int c = k0 + ac;
      float ri = rinv[t * NH + (c >> 7)];
      const u16* op = ob + t * PP + c;
      const u16* gp = g2 + t * PP + c;
#pragma unroll
      for (int e = 0; e < 8; ++e) {
        float a = b2f(op[e]) * ri * wn[(c & 127) + e] * fsig(b2f(gp[e]));
        u16 hh = f2b(a);
        ahi[e] = hh;
        alo[e] = f2b(a - b2f(hh));
      }
      const float* bpp = Wo + (long)(k0 + br) * N + bn + bc;
#pragma unroll
      for (int e = 0; e < 8; ++e) {
        float x = bpp[e];
        u16 hh = f2b(x);
        bhi8[e] = hh;
        blo8[e] = f2b(x - b2f(hh));
      }
    }
    __syncthreads();
    *(float4*)&As[0][ar][ac] = *(float4*)ahi;
    *(float4*)&As[1][ar][ac] = *(float4*)alo;
    *(float4*)&Bs[0][br][bc] = *(float4*)bhi8;
    *(float4*)&Bs[1][br][bc] = *(float4*)blo8;
    __syncthreads();
    short8 afh[2], afl[2], bfh[2], bfl[2];
#pragma unroll
    for (int i = 0; i < 2; ++i) {
      afh[i] = *(const short8*)&As[0][wm + i * 16 + r][q * 8];
      afl[i] = *(const short8*)&As[1][wm + i * 16 + r][q * 8];
    }
#pragma unroll
    for (int i = 0; i < 2; ++i) {
      short8 th, tl;
#pragma unroll
      for (int j = 0; j < 8; ++j) {
        th[j] = (short)Bs[0][q * 8 + j][wn_ + i * 16 + r];
        tl[j] = (short)Bs[1][q * 8 + j][wn_ + i * 16 + r];
      }
      bfh[i] = th; bfl[i] = tl;
    }
#pragma unroll
    for (int i = 0; i < 2; ++i)
#pragma unroll
      for (int j = 0; j < 2; ++j) {
        acc[i][j] = __builtin_amdgcn_mfma_f32_16x16x32_bf16(afh[i], bfh[j], acc[i][j], 0, 0, 0);
        acc[i][j] = __builtin_amdgcn_mfma_f32_16x16x32_bf16(afh[i], bfl[j], acc[i][j], 0, 0, 0);
        acc[i][j] = __builtin_amdgcn_mfma_f32_16x16x32_bf16(afl[i], bfh[j], acc[i][j], 0, 0, 0);
      }
  }
#pragma unroll
  for (int i = 0; i < 2; ++i)
#pragma unroll
    for (int j = 0; j < 2; ++j) {
      long col = bn + wn_ + j * 16 + r;
#pragma unroll
      for (int e = 0; e < 4; ++e) {
        long row = bm + wm + i * 16 + q * 4 + e;
        C[row * N + col] = acc[i][j][e];
      }
    }
}

extern "C" void kernel_launch(void* const* d_in, const int* in_sizes, int n_in,
                              void* d_out, int out_size, void* d_ws, size_t ws_size,
                              hipStream_t stream) {
  const float* hs   = (const float*)d_in[0];
  const float* Wq   = (const float*)d_in[1];
  const float* Wk   = (const float*)d_in[2];
  const float* Wv   = (const float*)d_in[3];
  const float* cq   = (const float*)d_in[4];
  const float* ck   = (const float*)d_in[5];
  const float* cv   = (const float*)d_in[6];
  const float* Wb   = (const float*)d_in[7];
  const float* Wfa  = (const float*)d_in[8];
  const float* Wfb  = (const float*)d_in[9];
  const float* dtb  = (const float*)d_in[10];
  const float* Alog = (const float*)d_in[11];
  const float* Wga  = (const float*)d_in[12];
  const float* Wgb  = (const float*)d_in[13];
  const float* wn   = (const float*)d_in[14];
  const float* Wo   = (const float*)d_in[15];

  char* ws = (char*)d_ws;
  dim3 blk(256);
  dim3 g_big(PP / 64, T_TOK / 64);
  dim3 g_thin(HD / 64, T_TOK / 64);
  const int EW = T_TOK * PP / 256;
  const float qscale = 0.08838834764831845f;  // HD^-0.5

  const size_t NEED = (size_t)227 << 20;   // same requirement rounds 5/6 proved
  if (ws_size >= NEED) {
    // ---- big path: fp32 q/k conv + fp32 exp-domain decay + half-wave scan ----
    float* qc   = (float*)(ws);                        // 64 MiB f32[T][P]
    float* kc   = (float*)(ws + ((size_t)64 << 20));   // 64 MiB
    float* egp  = (float*)(ws + ((size_t)128 << 20));  // 64 MiB (dead after scan)
    u16*   B2   = (u16*)(ws + ((size_t)192 << 20));    // raw v -> o in place, 32 MiB
    float* beta = (float*)(ws + ((size_t)224 << 20));             // 512 KiB
    float* rinv = (float*)(ws + ((size_t)224 << 20) + (512u << 10)); // 512 KiB
    u16*   hfa  = (u16*)(ws + ((size_t)225 << 20));    // 1 MiB
    u16*   hga  = (u16*)(ws + ((size_t)226 << 20));    // 1 MiB
    u16*   g1pre = (u16*)kc;        // bf16 32 MiB staged in kc region (consumed
                                    // by expg_f32 before conv k overwrites)
    u16*   G2   = (u16*)egp;        // g2pre bf16 32 MiB overlays dead eg region
    u16*   rawqk = (u16*)d_out;     // 32 MiB scratch for raw q then raw k;
                                    // gemm_final rewrites d_out at the end

    // g1 decay pipeline first (g1pre lives in kc region until consumed)
    gemm_k<0, 1, 1><<<g_thin, blk, 0, stream>>>(hs, Wfa, hfa, T_TOK, HD, HID);
    gemm_k<1, 0, 1><<<g_big, blk, 0, stream>>>(hfa, Wfb, g1pre, T_TOK, PP, HD);
    expg_f32_k<<<EW, blk, 0, stream>>>(g1pre, egp, dtb, Alog);
    // q projection -> conv+silu fp32 (qscale folded)
    gemm_k<0, 1, 1><<<g_big, blk, 0, stream>>>(hs, Wq, rawqk, T_TOK, PP, HID);
    conv_f32_k<<<T_TOK * PP / 8 / 256, blk, 0, stream>>>(rawqk, cq, qc, qscale);
    // k projection -> conv+silu fp32 (kc region: g1pre now dead)
    gemm_k<0, 1, 1><<<g_big, blk, 0, stream>>>(hs, Wk, rawqk, T_TOK, PP, HID);
    conv_f32_k<<<T_TOK * PP / 8 / 256, blk, 0, stream>>>(rawqk, ck, kc, 1.f);
    // v projection + beta + g2 first stage
    gemm_k<0, 1, 1><<<g_big, blk, 0, stream>>>(hs, Wv, B2, T_TOK, PP, HID);
    beta_k<<<T_TOK / 8, blk, 0, stream>>>(hs, Wb, beta);
    gemm_k<0, 1, 1><<<g_thin, blk, 0, stream>>>(hs, Wga, hga, T_TOK, HD, HID);
    // half-wave scan with XCD swizzle + register prefetch (o -> B2 in place)
    scan_half_k<<<NH * (HD / 2) / 4, blk, 0, stream>>>(qc, kc, B2, egp, beta, cv);
    // g2 second stage into dead eg region
    gemm_k<1, 0, 1><<<g_big, blk, 0, stream>>>(hga, Wgb, G2, T_TOK, PP, HD);
    rms_k<<<T_TOK * NH / 4, blk, 0, stream>>>(B2, rinv);
    gemm_final_k<<<dim3(HID / 64, T_TOK / 64), blk, 0, stream>>>(B2, G2, rinv, wn, Wo, (float*)d_out);
  } else {
    // ---- fallback: round-3 layout/path (131 MiB, measured-good) ----
    const size_t SZB = (size_t)T_TOK * PP * 2;
    u16*   B0   = (u16*)(ws + 0 * SZB);
    u16*   B1   = (u16*)(ws + 1 * SZB);
    u16*   B2   = (u16*)(ws + 2 * SZB);
    u16*   B3   = (u16*)(ws + 3 * SZB);
    float* beta = (float*)(ws + 4 * SZB);
    float* rinv = (float*)(ws + 4 * SZB + (512u << 10));
    u16*   hfa  = (u16*)(ws + 4 * SZB + (1u << 20));
    u16*   hga  = (u16*)(ws + 4 * SZB + (2u << 20));

    gemm_k<0, 1, 1><<<g_big, blk, 0, stream>>>(hs, Wq, B0, T_TOK, PP, HID);
    gemm_k<0, 1, 1><<<g_big, blk, 0, stream>>>(hs, Wk, B1, T_TOK, PP, HID);
    gemm_k<0, 1, 1><<<g_big, blk, 0, stream>>>(hs, Wv, B2, T_TOK, PP, HID);
    beta_k<<<T_TOK / 8, blk, 0, stream>>>(hs, Wb, beta);
    gemm_k<0, 1, 1><<<g_thin, blk, 0, stream>>>(hs, Wfa, hfa, T_TOK, HD, HID);
    gemm_k<1, 0, 1><<<g_big, blk, 0, stream>>>(hfa, Wfb, B3, T_TOK, PP, HD);
    expg_k<<<EW, blk, 0, stream>>>(B3, dtb, Alog);
    gemm_k<0, 1, 1><<<g_thin, blk, 0, stream>>>(hs, Wga, hga, T_TOK, HD, HID);
    scan_k<<<T_TOK / 4, blk, 0, stream>>>(B0, B1, B2, B3, beta, cq, ck, cv);
    gemm_k<1, 0, 1><<<g_big, blk, 0, stream>>>(hga, Wgb, B1, T_TOK, PP, HD);
    rms_k<<<T_TOK * NH / 4, blk, 0, stream>>>(B2, rinv);
    gemm_final_k<<<dim3(HID / 64, T_TOK / 64), blk, 0, stream>>>(B2, B1, rinv, wn, Wo, (float*)d_out);
  }
}

// Round 8
// 3733.331 us; speedup vs baseline: 1.6615x; 1.0085x over previous
//
#include <hip/hip_runtime.h>

#define T_TOK 4096
#define HID   2048
#define NH    32
#define HD    128
#define PP    4096

typedef unsigned short u16;
typedef unsigned int   u32;
typedef __attribute__((ext_vector_type(8))) short short8;
typedef __attribute__((ext_vector_type(4))) float floatx4;
typedef __attribute__((ext_vector_type(2))) unsigned int uint2v;

__device__ __forceinline__ float b2f(u16 u) {
  union { u32 i; float f; } x; x.i = ((u32)u) << 16; return x.f;
}
__device__ __forceinline__ u16 f2b(float f) {
  u32 x = __float_as_uint(f);
  u32 r = (x + 0x7fffu + ((x >> 16) & 1u)) >> 16;
  return (u16)r;
}
__device__ __forceinline__ float blo(u32 u) { return __uint_as_float(u << 16); }
__device__ __forceinline__ float bhi(u32 u) { return __uint_as_float(u & 0xffff0000u); }

// fast transcendentals: v_exp_f32 / v_rcp_f32 (~1ulp fp32 — far below bf16 noise)
__device__ __forceinline__ float fexp(float x) {
  return __builtin_amdgcn_exp2f(x * 1.4426950408889634f);
}
__device__ __forceinline__ float fsig(float x) {
  return __builtin_amdgcn_rcpf(1.f + fexp(-x));
}

// 64-lane sum broadcast (used by rms_k and the fallback scan).
__device__ __forceinline__ float wsum64(float x) {
  int t;
  t = __builtin_amdgcn_update_dpp(0, __float_as_int(x), 0x121, 0xf, 0xf, true);
  x += __int_as_float(t);
  t = __builtin_amdgcn_update_dpp(0, __float_as_int(x), 0x122, 0xf, 0xf, true);
  x += __int_as_float(t);
  t = __builtin_amdgcn_update_dpp(0, __float_as_int(x), 0x124, 0xf, 0xf, true);
  x += __int_as_float(t);
  t = __builtin_amdgcn_update_dpp(0, __float_as_int(x), 0x128, 0xf, 0xf, true);
  x += __int_as_float(t);
#if __has_builtin(__builtin_amdgcn_permlane16_swap)
  uint2v s = __builtin_amdgcn_permlane16_swap(__float_as_uint(x), __float_as_uint(x), false, false);
  x = __uint_as_float(s[0]) + __uint_as_float(s[1]);   // x[lane] + x[lane^16]
#else
  t = __builtin_amdgcn_ds_swizzle(__float_as_int(x), 0x401F); // lane ^ 16
  x += __int_as_float(t);
#endif
  uint2v p = __builtin_amdgcn_permlane32_swap(__float_as_uint(x), __float_as_uint(x), false, false);
  return __uint_as_float(p[0]) + __uint_as_float(p[1]);
}

// 32-lane-group sum broadcast: lanes 0-31 get their group's sum, lanes 32-63 theirs.
__device__ __forceinline__ float wsum32h(float x) {
  int t;
  t = __builtin_amdgcn_update_dpp(0, __float_as_int(x), 0x121, 0xf, 0xf, true);
  x += __int_as_float(t);
  t = __builtin_amdgcn_update_dpp(0, __float_as_int(x), 0x122, 0xf, 0xf, true);
  x += __int_as_float(t);
  t = __builtin_amdgcn_update_dpp(0, __float_as_int(x), 0x124, 0xf, 0xf, true);
  x += __int_as_float(t);
  t = __builtin_amdgcn_update_dpp(0, __float_as_int(x), 0x128, 0xf, 0xf, true);
  x += __int_as_float(t);
#if __has_builtin(__builtin_amdgcn_permlane16_swap)
  uint2v s = __builtin_amdgcn_permlane16_swap(__float_as_uint(x), __float_as_uint(x), false, false);
  return __uint_as_float(s[0]) + __uint_as_float(s[1]);   // x[lane] + x[lane^16]
#else
  t = __builtin_amdgcn_ds_swizzle(__float_as_int(x), 0x401F); // lane ^ 16 (per 32-group)
  return x + __int_as_float(t);
#endif
}

// ---- split prepass: fp32 -> packed (hi16 | lo16<<16), hi/lo via the SAME f2b
// sequence the GEMMs previously ran in-loop. Hoisting it here removes the 64x
// redundant re-conversion per element; GEMM results are BITWISE identical. ----
__global__ __launch_bounds__(256)
void split_k(const float* __restrict__ in, u32* __restrict__ out) {
  long i4 = ((long)blockIdx.x * 256 + threadIdx.x) * 4;
  float4 v = *(const float4*)(in + i4);
  u32 o[4];
#pragma unroll
  for (int e = 0; e < 4; ++e) {
    float x = ((const float*)&v)[e];
    u16 hh = f2b(x);
    u16 ll = f2b(x - b2f(hh));
    o[e] = (u32)hh | ((u32)ll << 16);
  }
  *(uint4*)(out + i4) = *(uint4*)o;
}

// ---------------- GEMM (fallback path): C = A * B, on-the-fly split ----------------
template<int ABF16, int ASPL, int BSPL>
__global__ __launch_bounds__(256)
void gemm_k(const void* __restrict__ Av, const float* __restrict__ B,
            u16* __restrict__ C, int M, int N, int K) {
  __shared__ u16 As[ASPL + 1][64][40];
  __shared__ u16 Bs[BSPL + 1][32][72];
  const int tid  = threadIdx.x;
  const int lane = tid & 63;
  const int wave = tid >> 6;
  const long bm = (long)blockIdx.y * 64;
  const long bn = (long)blockIdx.x * 64;
  const int wm = (wave >> 1) * 32;
  const int wn = (wave & 1) * 32;
  const int ar = tid >> 2, ac = (tid & 3) * 8;
  const int br = tid >> 3, bc = (tid & 7) * 8;
  const int q = lane >> 4, r = lane & 15;
  floatx4 acc[2][2];
#pragma unroll
  for (int i = 0; i < 2; ++i)
#pragma unroll
    for (int j = 0; j < 2; ++j) acc[i][j] = (floatx4)0.f;

  for (int k0 = 0; k0 < K; k0 += 32) {
    u16 ahi[8], alo[8], bhi8[8], blo8[8];
    if (ABF16) {
      const u16* A = (const u16*)Av;
      *(float4*)ahi = *(const float4*)(A + (bm + ar) * (long)K + k0 + ac);
    } else {
      const float* A = (const float*)Av;
      const float* ap = A + (bm + ar) * (long)K + k0 + ac;
#pragma unroll
      for (int e = 0; e < 8; ++e) {
        float x = ap[e];
        u16 hh = f2b(x);
        ahi[e] = hh;
        if (ASPL) alo[e] = f2b(x - b2f(hh));
      }
    }
    {
      const float* bp = B + (long)(k0 + br) * N + bn + bc;
#pragma unroll
      for (int e = 0; e < 8; ++e) {
        float x = bp[e];
        u16 hh = f2b(x);
        bhi8[e] = hh;
        if (BSPL) blo8[e] = f2b(x - b2f(hh));
      }
    }
    __syncthreads();
    *(float4*)&As[0][ar][ac] = *(float4*)ahi;
    *(float4*)&Bs[0][br][bc] = *(float4*)bhi8;
    if (ASPL) *(float4*)&As[ASPL][ar][ac] = *(float4*)alo;
    if (BSPL) *(float4*)&Bs[BSPL][br][bc] = *(float4*)blo8;
    __syncthreads();
    short8 afh[2], afl[2], bfh[2], bfl[2];
#pragma unroll
    for (int i = 0; i < 2; ++i) {
      afh[i] = *(const short8*)&As[0][wm + i * 16 + r][q * 8];
      if (ASPL) afl[i] = *(const short8*)&As[ASPL][wm + i * 16 + r][q * 8];
    }
#pragma unroll
    for (int i = 0; i < 2; ++i) {
      short8 th, tl;
#pragma unroll
      for (int j = 0; j < 8; ++j) {
        th[j] = (short)Bs[0][q * 8 + j][wn + i * 16 + r];
        if (BSPL) tl[j] = (short)Bs[BSPL][q * 8 + j][wn + i * 16 + r];
      }
      bfh[i] = th;
      if (BSPL) bfl[i] = tl;
    }
#pragma unroll
    for (int i = 0; i < 2; ++i)
#pragma unroll
      for (int j = 0; j < 2; ++j) {
        acc[i][j] = __builtin_amdgcn_mfma_f32_16x16x32_bf16(afh[i], bfh[j], acc[i][j], 0, 0, 0);
        if (BSPL) acc[i][j] = __builtin_amdgcn_mfma_f32_16x16x32_bf16(afh[i], bfl[j], acc[i][j], 0, 0, 0);
        if (ASPL) acc[i][j] = __builtin_amdgcn_mfma_f32_16x16x32_bf16(afl[i], bfh[j], acc[i][j], 0, 0, 0);
      }
  }
#pragma unroll
  for (int i = 0; i < 2; ++i)
#pragma unroll
    for (int j = 0; j < 2; ++j) {
      long col = bn + wn + j * 16 + r;
#pragma unroll
      for (int e = 0; e < 4; ++e) {
        long row = bm + wm + i * 16 + q * 4 + e;
        C[row * N + col] = f2b(acc[i][j][e]);
      }
    }
}

// ---------------- GEMM with PRE-SPLIT operands ----------------
// APRE=1: A is u32 (hi|lo<<16) presplit. APRE=0: A is plain bf16.
// B always u32 presplit. Unpack = 2 ops/elem (vs ~10 for in-loop f2b split);
// MFMA sequence/order identical to gemm_k — outputs bitwise identical.
template<int APRE>
__global__ __launch_bounds__(256)
void gemm_ps_k(const void* __restrict__ Av, const u32* __restrict__ B,
               u16* __restrict__ C, int M, int N, int K) {
  __shared__ u16 As[APRE + 1][64][40];
  __shared__ u16 Bs[2][32][72];
  const int tid  = threadIdx.x;
  const int lane = tid & 63;
  const int wave = tid >> 6;
  const long bm = (long)blockIdx.y * 64;
  const long bn = (long)blockIdx.x * 64;
  const int wm = (wave >> 1) * 32;
  const int wn = (wave & 1) * 32;
  const int ar = tid >> 2, ac = (tid & 3) * 8;
  const int br = tid >> 3, bc = (tid & 7) * 8;
  const int q = lane >> 4, r = lane & 15;
  floatx4 acc[2][2];
#pragma unroll
  for (int i = 0; i < 2; ++i)
#pragma unroll
    for (int j = 0; j < 2; ++j) acc[i][j] = (floatx4)0.f;

  for (int k0 = 0; k0 < K; k0 += 32) {
    u16 ahi[8], alo[8], bhi8[8], blo8[8];
    if (APRE) {
      const u32* A = (const u32*)Av;
      const u32* ap = A + (bm + ar) * (long)K + k0 + ac;
      uint4 a0 = *(const uint4*)ap;
      uint4 a1 = *(const uint4*)(ap + 4);
#pragma unroll
      for (int e = 0; e < 4; ++e) {
        u32 va = ((const u32*)&a0)[e], vb = ((const u32*)&a1)[e];
        ahi[e]     = (u16)va;  alo[e]     = (u16)(va >> 16);
        ahi[e + 4] = (u16)vb;  alo[e + 4] = (u16)(vb >> 16);
      }
    } else {
      const u16* A = (const u16*)Av;
      *(float4*)ahi = *(const float4*)(A + (bm + ar) * (long)K + k0 + ac);
    }
    {
      const u32* bp = B + (long)(k0 + br) * N + bn + bc;
      uint4 b0 = *(const uint4*)bp;
      uint4 b1 = *(const uint4*)(bp + 4);
#pragma unroll
      for (int e = 0; e < 4; ++e) {
        u32 va = ((const u32*)&b0)[e], vb = ((const u32*)&b1)[e];
        bhi8[e]     = (u16)va;  blo8[e]     = (u16)(va >> 16);
        bhi8[e + 4] = (u16)vb;  blo8[e + 4] = (u16)(vb >> 16);
      }
    }
    __syncthreads();
    *(float4*)&As[0][ar][ac] = *(float4*)ahi;
    if (APRE) *(float4*)&As[APRE][ar][ac] = *(float4*)alo;
    *(float4*)&Bs[0][br][bc] = *(float4*)bhi8;
    *(float4*)&Bs[1][br][bc] = *(float4*)blo8;
    __syncthreads();
    short8 afh[2], afl[2], bfh[2], bfl[2];
#pragma unroll
    for (int i = 0; i < 2; ++i) {
      afh[i] = *(const short8*)&As[0][wm + i * 16 + r][q * 8];
      if (APRE) afl[i] = *(const short8*)&As[APRE][wm + i * 16 + r][q * 8];
    }
#pragma unroll
    for (int i = 0; i < 2; ++i) {
      short8 th, tl;
#pragma unroll
      for (int j = 0; j < 8; ++j) {
        th[j] = (short)Bs[0][q * 8 + j][wn + i * 16 + r];
        tl[j] = (short)Bs[1][q * 8 + j][wn + i * 16 + r];
      }
      bfh[i] = th; bfl[i] = tl;
    }
#pragma unroll
    for (int i = 0; i < 2; ++i)
#pragma unroll
      for (int j = 0; j < 2; ++j) {
        acc[i][j] = __builtin_amdgcn_mfma_f32_16x16x32_bf16(afh[i], bfh[j], acc[i][j], 0, 0, 0);
        acc[i][j] = __builtin_amdgcn_mfma_f32_16x16x32_bf16(afh[i], bfl[j], acc[i][j], 0, 0, 0);
        if (APRE) acc[i][j] = __builtin_amdgcn_mfma_f32_16x16x32_bf16(afl[i], bfh[j], acc[i][j], 0, 0, 0);
      }
  }
#pragma unroll
  for (int i = 0; i < 2; ++i)
#pragma unroll
    for (int j = 0; j < 2; ++j) {
      long col = bn + wn + j * 16 + r;
#pragma unroll
      for (int e = 0; e < 4; ++e) {
        long row = bm + wm + i * 16 + q * 4 + e;
        C[row * N + col] = f2b(acc[i][j][e]);
      }
    }
}

// ---------------- beta = 2*sigmoid(hs @ Wb)  [T,32] f32 ----------------
__global__ __launch_bounds__(256)
void beta_k(const float* __restrict__ hs, const float* __restrict__ Wb, float* __restrict__ beta) {
  int t = blockIdx.x * 8 + (threadIdx.x >> 5);
  int h = threadIdx.x & 31;
  const float* hrow = hs + (long)t * HID;
  float acc = 0.f;
  for (int k = 0; k < HID; ++k)
    acc += hrow[k] * Wb[k * NH + h];
  beta[t * NH + h] = 2.f * fsig(acc);
}

// ---- x = -5*sigmoid(exp(A_log[h]) * (g1pre + dt_bias)) in place bf16 (fallback) ----
__global__ __launch_bounds__(256)
void expg_k(u16* __restrict__ g1, const float* __restrict__ dtb, const float* __restrict__ Alog) {
  int idx = blockIdx.x * 256 + threadIdx.x;
  int p = idx & (PP - 1);
  int h = p >> 7;
  float g = b2f(g1[idx]) + dtb[p];
  float a = fexp(Alog[h]);
  g1[idx] = f2b(-5.f * fsig(a * g));
}

// ---- decay prepass, EXP-domain FP32 out (bitwise = in-scan fexp(bf16 x)) ----
__global__ __launch_bounds__(256)
void expg_f32_k(const u16* __restrict__ g1, float* __restrict__ eg,
                const float* __restrict__ dtb, const float* __restrict__ Alog) {
  int idx = blockIdx.x * 256 + threadIdx.x;
  int p = idx & (PP - 1);
  int h = p >> 7;
  float g = b2f(g1[idx]) + dtb[p];
  float a = fexp(Alog[h]);
  float x = -5.f * fsig(a * g);
  eg[idx] = fexp(b2f(f2b(x)));
}

// ------- causal conv(K=4)+SiLU(+scale) prepass, FP32 output -------
__global__ __launch_bounds__(256)
void conv_f32_k(const u16* __restrict__ x, const float* __restrict__ w,
                float* __restrict__ out, float scale) {
  int idx = blockIdx.x * 256 + threadIdx.x;   // T * P/8 threads
  int t = idx >> 9;                           // P/8 = 512
  int c8 = (idx & 511) << 3;
  short8 r0, r1, r2, r3;
  r3 = *(const short8*)(x + (long)t * PP + c8);
  r2 = (t >= 1) ? *(const short8*)(x + (long)(t - 1) * PP + c8) : (short8)0;
  r1 = (t >= 2) ? *(const short8*)(x + (long)(t - 2) * PP + c8) : (short8)0;
  r0 = (t >= 3) ? *(const short8*)(x + (long)(t - 3) * PP + c8) : (short8)0;
  const float4* wv = (const float4*)(w + (long)c8 * 4);
  float o[8];
#pragma unroll
  for (int e = 0; e < 8; ++e) {
    float4 we = wv[e];
    float s = we.x * b2f((u16)r0[e]) + we.y * b2f((u16)r1[e])
            + we.z * b2f((u16)r2[e]) + we.w * b2f((u16)r3[e]);
    o[e] = s * fsig(s) * scale;
  }
  *(float4*)(out + (long)t * PP + c8)     = *(float4*)&o[0];
  *(float4*)(out + (long)t * PP + c8 + 4) = *(float4*)&o[4];
}

// ---------------- gated delta-rule scan (round-7, unchanged) ----------------
__global__ __launch_bounds__(256)
void scan_half_k(const float* __restrict__ qc, const float* __restrict__ kc,
                 u16* __restrict__ prev, const float* __restrict__ eg,
                 const float* __restrict__ beta, const float* __restrict__ cvw) {
  const int bid = blockIdx.x;                       // 512 blocks
  const int h   = (bid & 7) * 4 + (bid >> 7);       // head 0..31 (16 blocks/head, same bid%8)
  const int p   = ((bid >> 3) & 15) * 4 + (threadIdx.x >> 6);  // pair 0..63
  const int lane = threadIdx.x & 63;
  const int hf = lane >> 5;                 // half index
  const int l5 = lane & 31;
  const int c0  = h * HD + l5 * 4;          // 4 channels per lane (same both halves)
  const int cv0 = h * HD + 2 * p + hf;      // column per half (uniform within half)
  float vw0 = cvw[cv0 * 4 + 0], vw1 = cvw[cv0 * 4 + 1];
  float vw2 = cvw[cv0 * 4 + 2], vw3 = cvw[cv0 * 4 + 3];
  const long RS = PP / 4;                   // float4 row stride
  const float4* qp = (const float4*)(qc + c0);
  const float4* kp = (const float4*)(kc + c0);
  const float4* ep = (const float4*)(eg + c0);
  u16* vp = prev + cv0;
  const float* bp = beta + h;
  float hv0 = 0.f, hv1 = 0.f, hv2 = 0.f;
  float S0 = 0.f, S1 = 0.f, S2 = 0.f, S3 = 0.f;

  float4 cq[4], ck4[4], ce[4];
  float  cvr[4], cb[4];
#pragma unroll
  for (int i = 0; i < 4; ++i) {
    cq[i]  = qp[(long)i * RS];
    ck4[i] = kp[(long)i * RS];
    ce[i]  = ep[(long)i * RS];
    cvr[i] = b2f(vp[(long)i * PP]);
    cb[i]  = bp[i * NH];
  }

  for (int tb = 0; tb < T_TOK; tb += 4) {
    float4 nq[4], nk[4], ne[4];
    float  nv[4], nb[4];
#pragma unroll
    for (int i = 0; i < 4; ++i) {
      nq[i] = qp[(long)(i + 4) * RS];
      nk[i] = kp[(long)(i + 4) * RS];
      ne[i] = ep[(long)(i + 4) * RS];
      nv[i] = b2f(vp[(long)(i + 4) * PP]);
      nb[i] = bp[(i + 4) * NH];
    }
#pragma unroll
    for (int i = 0; i < 4; ++i) {
      float vraw = cvr[i];
      float bt = cb[i];
      float4 qv = cq[i], kv = ck4[i], ev = ce[i];
      float cvv = vw3 * vraw + vw2 * hv0 + vw1 * hv1 + vw0 * hv2;
      hv2 = hv1; hv1 = hv0; hv0 = vraw;
      float vv = cvv * fsig(cvv);
      S0 *= ev.x; S1 *= ev.y; S2 *= ev.z; S3 *= ev.w;
      float pr = wsum32h(fmaf(kv.x, S0, fmaf(kv.y, S1, fmaf(kv.z, S2, kv.w * S3))));
      float u = bt * (vv - pr);
      S0 = fmaf(kv.x, u, S0); S1 = fmaf(kv.y, u, S1);
      S2 = fmaf(kv.z, u, S2); S3 = fmaf(kv.w, u, S3);
      float o = wsum32h(fmaf(qv.x, S0, fmaf(qv.y, S1, fmaf(qv.z, S2, qv.w * S3))));
      if (l5 == 0) vp[(long)i * PP] = f2b(o);
    }
#pragma unroll
    for (int i = 0; i < 4; ++i) {
      cq[i] = nq[i]; ck4[i] = nk[i]; ce[i] = ne[i]; cvr[i] = nv[i]; cb[i] = nb[i];
    }
    qp += 4 * RS; kp += 4 * RS; ep += 4 * RS; vp += (long)4 * PP; bp += 4 * NH;
  }
}

// ---------------- fused conv+silu + scan (round-3 fallback) ----------------
__global__ __launch_bounds__(256)
void scan_k(const u16* __restrict__ preq, const u16* __restrict__ prek,
            u16* __restrict__ prev, const u16* __restrict__ gx,
            const float* __restrict__ beta,
            const float* __restrict__ cqw, const float* __restrict__ ckw,
            const float* __restrict__ cvw) {
  int wid  = blockIdx.x * 4 + (threadIdx.x >> 6);  // h*128 + vc
  int lane = threadIdx.x & 63;
  int h = wid >> 7, vc = wid & 127;
  int c0  = h * HD + 2 * lane;
  int cv0 = h * HD + vc;
  float qw[4][2], kw[4][2], vw[4];
#pragma unroll
  for (int j = 0; j < 4; ++j) {
    qw[j][0] = cqw[c0 * 4 + j];       qw[j][1] = cqw[(c0 + 1) * 4 + j];
    kw[j][0] = ckw[c0 * 4 + j];       kw[j][1] = ckw[(c0 + 1) * 4 + j];
    vw[j]    = cvw[cv0 * 4 + j];
  }
  const u32* q32 = (const u32*)preq;
  const u32* k32 = (const u32*)prek;
  const u32* x32 = (const u32*)gx;
  float hq0x = 0.f, hq0y = 0.f, hq1x = 0.f, hq1y = 0.f, hq2x = 0.f, hq2y = 0.f;
  float hk0x = 0.f, hk0y = 0.f, hk1x = 0.f, hk1y = 0.f, hk2x = 0.f, hk2y = 0.f;
  float hv0 = 0.f, hv1 = 0.f, hv2 = 0.f;
  float Sx = 0.f, Sy = 0.f;
  const float qscale = 0.08838834764831845f;  // HD^-0.5
#pragma unroll 4
  for (int t = 0; t < T_TOK; ++t) {
    int rb = t * (PP / 2) + h * 64 + lane;
    u32 qr = q32[rb], kr = k32[rb], xr = x32[rb];
    float vraw = b2f(prev[t * PP + cv0]);
    float bt = beta[t * NH + h];
    float qx = blo(qr), qy = bhi(qr);
    float kx = blo(kr), ky = bhi(kr);
    float cq0 = qw[3][0] * qx + qw[2][0] * hq0x + qw[1][0] * hq1x + qw[0][0] * hq2x;
    float cq1 = qw[3][1] * qy + qw[2][1] * hq0y + qw[1][1] * hq1y + qw[0][1] * hq2y;
    float ck0 = kw[3][0] * kx + kw[2][0] * hk0x + kw[1][0] * hk1x + kw[0][0] * hk2x;
    float ck1 = kw[3][1] * ky + kw[2][1] * hk0y + kw[1][1] * hk1y + kw[0][1] * hk2y;
    float cvv = vw[3] * vraw + vw[2] * hv0 + vw[1] * hv1 + vw[0] * hv2;
    hq2x = hq1x; hq1x = hq0x; hq0x = qx;
    hq2y = hq1y; hq1y = hq0y; hq0y = qy;
    hk2x = hk1x; hk1x = hk0x; hk0x = kx;
    hk2y = hk1y; hk1y = hk0y; hk0y = ky;
    hv2 = hv1; hv1 = hv0; hv0 = vraw;
    float qv0 = cq0 * fsig(cq0) * qscale;
    float qv1 = cq1 * fsig(cq1) * qscale;
    float kv0 = ck0 * fsig(ck0);
    float kv1 = ck1 * fsig(ck1);
    float vv  = cvv * fsig(cvv);
    Sx *= fexp(blo(xr)); Sy *= fexp(bhi(xr));
    float pr = wsum64(fmaf(kv0, Sx, kv1 * Sy));
    float u = bt * (vv - pr);
    Sx = fmaf(kv0, u, Sx);
    Sy = fmaf(kv1, u, Sy);
    float o = wsum64(fmaf(qv0, Sx, qv1 * Sy));
    if (lane == 0) prev[t * PP + cv0] = f2b(o);
  }
}

// ---------------- rinv[t,h] = rsqrt(mean(o^2) + eps) ----------------
__global__ __launch_bounds__(256)
void rms_k(const u16* __restrict__ ob, float* __restrict__ rinv) {
  int wid  = blockIdx.x * 4 + (threadIdx.x >> 6);  // t*32 + h
  int lane = threadIdx.x & 63;
  u32 o2 = ((const u32*)ob)[(long)wid * 64 + lane];
  float ox = blo(o2), oy = bhi(o2);
  float ss = wsum64(ox * ox + oy * oy);
  if (lane == 0) rinv[wid] = rsqrtf(ss * (1.f / 128.f) + 1e-5f);
}

// ---------------- final GEMM with fused gated-RMSNorm A-staging (unchanged) ----------------
__global__ __launch_bounds__(256)
void gemm_final_k(const u16* __restrict__ ob, const u16* __restrict__ g2,
                  const float* __restrict__ rinv, const float* __restrict__ wn,
                  const float* __restrict__ Wo, float* __restrict__ C) {
  __shared__ u16 As[2][64][40];
  __shared__ u16 Bs[2][32][72];
  const int tid  = threadIdx.x;
  const int lane = tid & 63;
  const int wave = tid >> 6;
  const long bm = (long)blockIdx.y * 64;
  const long bn = (long)blockIdx.x * 64;
  const int wm = (wave >> 1) * 32;
  const int wn_ = (wave & 1) * 32;
  const int ar = tid >> 2, ac = (tid & 3) * 8;
  const int br = tid >> 3, bc = (tid & 7) * 8;
  const int q = lane >> 4, r = lane & 15;
  const int N = HID, K = PP;
  floatx4 acc[2][2];
#pragma unroll
  for (int i = 0; i < 2; ++i)
#pragma unroll
    for (int j = 0; j < 2; ++j) acc[i][j] = (floatx4)0.f;

  for (int k0 = 0; k0 < K; k0 += 32) {
    u16 ahi[8], alo[8], bhi8[8], blo8[8];
    {
      long t = bm + ar;
      int c = k0 + ac;
      float ri = rinv[t * NH + (c >> 7)];
      const u16* op = ob + t * PP + c;
      const u16* gp = g2 + t * PP + c;
#pragma unroll
      for (int e = 0; e < 8; ++e) {
        float a = b2f(op[e]) * ri * wn[(c & 127) + e] * fsig(b2f(gp[e]));
        u16 hh = f2b(a);
        ahi[e] = hh;
        alo[e] = f2b(a - b2f(hh));
      }
      const float* bpp = Wo + (long)(k0 + br) * N + bn + bc;
#pragma unroll
      for (int e = 0; e < 8; ++e) {
        float x = bpp[e];
        u16 hh = f2b(x);
        bhi8[e] = hh;
        blo8[e] = f2b(x - b2f(hh));
      }
    }
    __syncthreads();
    *(float4*)&As[0][ar][ac] = *(float4*)ahi;
    *(float4*)&As[1][ar][ac] = *(float4*)alo;
    *(float4*)&Bs[0][br][bc] = *(float4*)bhi8;
    *(float4*)&Bs[1][br][bc] = *(float4*)blo8;
    __syncthreads();
    short8 afh[2], afl[2], bfh[2], bfl[2];
#pragma unroll
    for (int i = 0; i < 2; ++i) {
      afh[i] = *(const short8*)&As[0][wm + i * 16 + r][q * 8];
      afl[i] = *(const short8*)&As[1][wm + i * 16 + r][q * 8];
    }
#pragma unroll
    for (int i = 0; i < 2; ++i) {
      short8 th, tl;
#pragma unroll
      for (int j = 0; j < 8; ++j) {
        th[j] = (short)Bs[0][q * 8 + j][wn_ + i * 16 + r];
        tl[j] = (short)Bs[1][q * 8 + j][wn_ + i * 16 + r];
      }
      bfh[i] = th; bfl[i] = tl;
    }
#pragma unroll
    for (int i = 0; i < 2; ++i)
#pragma unroll
      for (int j = 0; j < 2; ++j) {
        acc[i][j] = __builtin_amdgcn_mfma_f32_16x16x32_bf16(afh[i], bfh[j], acc[i][j], 0, 0, 0);
        acc[i][j] = __builtin_amdgcn_mfma_f32_16x16x32_bf16(afh[i], bfl[j], acc[i][j], 0, 0, 0);
        acc[i][j] = __builtin_amdgcn_mfma_f32_16x16x32_bf16(afl[i], bfh[j], acc[i][j], 0, 0, 0);
      }
  }
#pragma unroll
  for (int i = 0; i < 2; ++i)
#pragma unroll
    for (int j = 0; j < 2; ++j) {
      long col = bn + wn_ + j * 16 + r;
#pragma unroll
      for (int e = 0; e < 4; ++e) {
        long row = bm + wm + i * 16 + q * 4 + e;
        C[row * N + col] = acc[i][j][e];
      }
    }
}

extern "C" void kernel_launch(void* const* d_in, const int* in_sizes, int n_in,
                              void* d_out, int out_size, void* d_ws, size_t ws_size,
                              hipStream_t stream) {
  const float* hs   = (const float*)d_in[0];
  const float* Wq   = (const float*)d_in[1];
  const float* Wk   = (const float*)d_in[2];
  const float* Wv   = (const float*)d_in[3];
  const float* cq   = (const float*)d_in[4];
  const float* ck   = (const float*)d_in[5];
  const float* cv   = (const float*)d_in[6];
  const float* Wb   = (const float*)d_in[7];
  const float* Wfa  = (const float*)d_in[8];
  const float* Wfb  = (const float*)d_in[9];
  const float* dtb  = (const float*)d_in[10];
  const float* Alog = (const float*)d_in[11];
  const float* Wga  = (const float*)d_in[12];
  const float* Wgb  = (const float*)d_in[13];
  const float* wn   = (const float*)d_in[14];
  const float* Wo   = (const float*)d_in[15];

  char* ws = (char*)d_ws;
  dim3 blk(256);
  dim3 g_big(PP / 64, T_TOK / 64);
  dim3 g_thin(HD / 64, T_TOK / 64);
  const int EW = T_TOK * PP / 256;
  const float qscale = 0.08838834764831845f;  // HD^-0.5

  const size_t NEED = (size_t)227 << 20;   // same requirement rounds 5-7 proved
  if (ws_size >= NEED) {
    // ---- big path layout (227 MiB, staged overlays) ----
    // [0,64)    qc fp32
    // [64,128)  kc fp32
    // [128,192) C region: pre-expg = hs32(32) + weight staging(<=34);
    //           expg..scan = egp fp32(64); post-scan = G2(32) + wgb32(2)
    // [192,224) B2: raw v -> o in place
    // [224,227) beta/rinv/hfa/hga
    float* qc    = (float*)(ws);
    float* kc    = (float*)(ws + ((size_t)64 << 20));
    char*  Creg  = ws + ((size_t)128 << 20);
    u32*   hs32  = (u32*)(Creg);                       // 32 MiB
    u32*   wst   = (u32*)(Creg + ((size_t)32 << 20));  // 32 MiB weight staging
    u32*   wfa32 = (u32*)(Creg + ((size_t)32 << 20));  // 1 MiB
    u32*   wga32 = (u32*)(Creg + ((size_t)33 << 20));  // 1 MiB
    u32*   wfb32 = (u32*)(Creg + ((size_t)34 << 20));  // 2 MiB
    float* egp   = (float*)(Creg);                     // 64 MiB (after hs32/wst dead)
    u16*   G2    = (u16*)(Creg);                       // 32 MiB (after egp dead)
    u32*   wgb32 = (u32*)(Creg + ((size_t)32 << 20));  // 2 MiB (after egp dead)
    u16*   B2    = (u16*)(ws + ((size_t)192 << 20));
    float* beta  = (float*)(ws + ((size_t)224 << 20));
    float* rinv  = (float*)(ws + ((size_t)224 << 20) + (512u << 10));
    u16*   hfa   = (u16*)(ws + ((size_t)225 << 20));
    u16*   hga   = (u16*)(ws + ((size_t)226 << 20));
    u16*   rawqk = (u16*)d_out;  // 32 MiB scratch (raw q, raw k, g1pre);
                                 // gemm_final rewrites d_out at the very end

    const int NHS = T_TOK * HID / 1024;   // 8192 blocks: 8M elems
    const int NWB = HID * PP / 1024;      // 8192: Wq/Wk/Wv
    const int NWT = HID * HD / 1024;      // 256: Wfa/Wga
    const int NWF = HD * PP / 1024;       // 512: Wfb/Wgb

    // pre-split hs once (used by q/k/v/fa/ga GEMMs)
    split_k<<<NHS, blk, 0, stream>>>(hs, hs32);
    // q projection
    split_k<<<NWB, blk, 0, stream>>>(Wq, wst);
    gemm_ps_k<1><<<g_big, blk, 0, stream>>>(hs32, wst, rawqk, T_TOK, PP, HID);
    conv_f32_k<<<T_TOK * PP / 8 / 256, blk, 0, stream>>>(rawqk, cq, qc, qscale);
    // k projection
    split_k<<<NWB, blk, 0, stream>>>(Wk, wst);
    gemm_ps_k<1><<<g_big, blk, 0, stream>>>(hs32, wst, rawqk, T_TOK, PP, HID);
    conv_f32_k<<<T_TOK * PP / 8 / 256, blk, 0, stream>>>(rawqk, ck, kc, 1.f);
    // v projection
    split_k<<<NWB, blk, 0, stream>>>(Wv, wst);
    gemm_ps_k<1><<<g_big, blk, 0, stream>>>(hs32, wst, B2, T_TOK, PP, HID);
    // beta
    beta_k<<<T_TOK / 8, blk, 0, stream>>>(hs, Wb, beta);
    // thin stages
    split_k<<<NWT, blk, 0, stream>>>(Wfa, wfa32);
    gemm_ps_k<1><<<g_thin, blk, 0, stream>>>(hs32, wfa32, hfa, T_TOK, HD, HID);
    split_k<<<NWT, blk, 0, stream>>>(Wga, wga32);
    gemm_ps_k<1><<<g_thin, blk, 0, stream>>>(hs32, wga32, hga, T_TOK, HD, HID);
    // g1 second stage + decay prepass (hs32 now dead; egp overwrites C region)
    split_k<<<NWF, blk, 0, stream>>>(Wfb, wfb32);
    gemm_ps_k<0><<<g_big, blk, 0, stream>>>(hfa, wfb32, rawqk, T_TOK, PP, HD);
    expg_f32_k<<<EW, blk, 0, stream>>>(rawqk, egp, dtb, Alog);
    // scan (o -> B2 in place)
    scan_half_k<<<NH * (HD / 2) / 4, blk, 0, stream>>>(qc, kc, B2, egp, beta, cv);
    // g2 second stage (egp dead; G2/wgb32 overlay C region)
    split_k<<<NWF, blk, 0, stream>>>(Wgb, wgb32);
    gemm_ps_k<0><<<g_big, blk, 0, stream>>>(hga, wgb32, G2, T_TOK, PP, HD);
    // rms + final
    rms_k<<<T_TOK * NH / 4, blk, 0, stream>>>(B2, rinv);
    gemm_final_k<<<dim3(HID / 64, T_TOK / 64), blk, 0, stream>>>(B2, G2, rinv, wn, Wo, (float*)d_out);
  } else {
    // ---- fallback: round-3 layout/path (131 MiB, measured-good) ----
    const size_t SZB = (size_t)T_TOK * PP * 2;
    u16*   B0   = (u16*)(ws + 0 * SZB);
    u16*   B1   = (u16*)(ws + 1 * SZB);
    u16*   B2   = (u16*)(ws + 2 * SZB);
    u16*   B3   = (u16*)(ws + 3 * SZB);
    float* beta = (float*)(ws + 4 * SZB);
    float* rinv = (float*)(ws + 4 * SZB + (512u << 10));
    u16*   hfa  = (u16*)(ws + 4 * SZB + (1u << 20));
    u16*   hga  = (u16*)(ws + 4 * SZB + (2u << 20));

    gemm_k<0, 1, 1><<<g_big, blk, 0, stream>>>(hs, Wq, B0, T_TOK, PP, HID);
    gemm_k<0, 1, 1><<<g_big, blk, 0, stream>>>(hs, Wk, B1, T_TOK, PP, HID);
    gemm_k<0, 1, 1><<<g_big, blk, 0, stream>>>(hs, Wv, B2, T_TOK, PP, HID);
    beta_k<<<T_TOK / 8, blk, 0, stream>>>(hs, Wb, beta);
    gemm_k<0, 1, 1><<<g_thin, blk, 0, stream>>>(hs, Wfa, hfa, T_TOK, HD, HID);
    gemm_k<1, 0, 1><<<g_big, blk, 0, stream>>>(hfa, Wfb, B3, T_TOK, PP, HD);
    expg_k<<<EW, blk, 0, stream>>>(B3, dtb, Alog);
    gemm_k<0, 1, 1><<<g_thin, blk, 0, stream>>>(hs, Wga, hga, T_TOK, HD, HID);
    scan_k<<<T_TOK / 4, blk, 0, stream>>>(B0, B1, B2, B3, beta, cq, ck, cv);
    gemm_k<1, 0, 1><<<g_big, blk, 0, stream>>>(hga, Wgb, B1, T_TOK, PP, HD);
    rms_k<<<T_TOK * NH / 4, blk, 0, stream>>>(B2, rinv);
    gemm_final_k<<<dim3(HID / 64, T_TOK / 64), blk, 0, stream>>>(B2, B1, rinv, wn, Wo, (float*)d_out);
  }
}